// Round 11
// baseline (680.875 us; speedup 1.0000x reference)
//
#include <hip/hip_runtime.h>

// Problem constants: B=2, C=96, D=H=W=40, S=64000, NH=4, HD=24, L=40
// Exact simplifications vs reference:
//  - pos_attn branch dropped (softmax row-shift invariance)
//  - R6 rotations dropped (R orthogonal; (Rq).(Rk) = q.k; v unrotated)
//  - mod1@ (lp2@B + b2) + b1 folded to W'@B + b'  (W' = mod1@lp2, exact)
// History: r7 XCD swizzle (FETCH 62->16.5MB). r13(v7): A via global_load_lds
// dbuf -> 98us. r16(v8b): compact tables (bsh moved OUT of st range after the
// v8 NaN) -> 90us, total 649.6 (best). Occupancy stayed 18.6%: GRID-capped
// (500 blocks / 256 CU ~= 2/CU), not LDS-capped.
// r17(v9): same 500 x 256-s tiles, but 512-thread blocks (8 waves x 1 B-tile,
// 96m x 32s each): waves/CU 8 -> 16 with ZERO added memory traffic (A DMA
// re-sliced k=wv+8i; B line count unchanged). Doubled latency hiding.

typedef __attribute__((ext_vector_type(8))) _Float16 half8;
typedef __attribute__((ext_vector_type(2))) _Float16 half2;
typedef __attribute__((ext_vector_type(16))) float floatx16;

static __device__ __forceinline__ half2 h2(unsigned int u) {
    return __builtin_bit_cast(half2, u);
}
static __device__ __forceinline__ float fdot2(unsigned int a, unsigned int b, float c) {
    return __builtin_amdgcn_fdot2(h2(a), h2(b), c, false);
}

typedef __attribute__((address_space(1))) const void gas_t;
typedef __attribute__((address_space(3))) void las_t;
static __device__ __forceinline__ void gll16(const void* g, void* l) {
    __builtin_amdgcn_global_load_lds((gas_t*)g, (las_t*)l, 16, 0, 0);
}

// ---------------- prep: pos fp32 [b][c][s] -> f16 [b][s][c], XCD-aligned ----------------
__global__ __launch_bounds__(256) void k_cvt_in(const float* __restrict__ pos,
                                                _Float16* __restrict__ in_t) {
    __shared__ _Float16 lds[64][97];
    int bid = blockIdx.x;
    int xcd = bid & 7, k = bid >> 3;      // k 0..251
    int L;
    if (xcd < 4) L = xcd * 63 + (k >> 2);
    else { if (k >= 248) return; L = 252 + (xcd - 4) * 62 + (k >> 2); }
    int q = k & 3;
    int b = L / 250;
    int s0 = (L % 250) * 256 + q * 64;
    int t = threadIdx.x;
    for (int i = t; i < 6144; i += 256) {
        int c = i / 64, sl = i % 64;
        lds[sl][c] = (_Float16)pos[(b * 96 + c) * 64000 + s0 + sl];
    }
    __syncthreads();
    _Float16* outp = in_t + ((size_t)b * 64000 + s0) * 96;
    for (int i = t; i < 6144; i += 256) {
        int sl = i / 96, c = i % 96;
        outp[i] = lds[sl][c];
    }
}

// ---------------- prep: lp1_w [o][c][tap] -> f16 wf [tap][o][c]; block 0 zeroes raw ----------------
__global__ void k_cvt_w(const float* __restrict__ w, _Float16* __restrict__ wf,
                        float* __restrict__ raw) {
    int i = blockIdx.x * 256 + threadIdx.x;
    if (i < 248832) {
        int c = i % 96, m = (i / 96) % 96, tap = i / 9216;
        wf[i] = (_Float16)w[(m * 96 + c) * 27 + tap];
    }
    if (blockIdx.x == 0) {
        for (int u = threadIdx.x; u < 768; u += 256) raw[u] = 0.f;
    }
}

// ---------------- prep: f32 -> f16 straight copy ----------------
__global__ void k_cvt_f16(const float* __restrict__ w, _Float16* __restrict__ o, int n) {
    int i = blockIdx.x * 256 + threadIdx.x;
    if (i < n) o[i] = (_Float16)w[i];
}

// ---------------- prep: W' = mod1_w @ lp2_w (f16), b' = mod1_w @ lp2_b + mod1_b ----------------
__global__ __launch_bounds__(256) void k_fold(const float* __restrict__ lp2_w,
                                              const float* __restrict__ lp2_b,
                                              const float* __restrict__ mod1_w,
                                              const float* __restrict__ mod1_b,
                                              _Float16* __restrict__ wfold,
                                              float* __restrict__ bfold) {
    int i = blockIdx.x * 256 + threadIdx.x;   // grid 36 -> 9216 outputs
    if (i < 9216) {
        int o = i / 96, c = i % 96;
        float a = 0.f;
        for (int k = 0; k < 96; k++) a += mod1_w[o * 96 + k] * lp2_w[k * 96 + c];
        wfold[i] = (_Float16)a;
    }
    if (blockIdx.x == 0 && threadIdx.x < 96) {
        int o = threadIdx.x;
        float a = mod1_b[o];
        for (int k = 0; k < 96; k++) a += mod1_w[o * 96 + k] * lp2_b[k];
        bfold[o] = a;
    }
}

// ---------------- conv 3x3x3 circular: 8-wave blocks, A via global_load_lds dbuf ----------------
// v9: 512 threads (8 waves x 1 B-tile of 96m x 32s). Same tiles, same traffic,
// 2x waves/CU (16) for latency hiding. A DMA re-sliced k = wv + 8*i.
__global__ __launch_bounds__(512) void k_conv3_v9(const _Float16* __restrict__ in_t,
                                                  const _Float16* __restrict__ wf,  // [tap][m][c]
                                                  const float* __restrict__ bias,
                                                  _Float16* __restrict__ c3) {
    // smem: adh int[9][256] @0 (9216) | A dbuf 2x18432 @9216 (ends 46080)
    //       | bsh float[96] @50176 (384). Epilogue st f16[256*98] @0 (50176).
    __shared__ __align__(16) char smem[50560];
    int* adh = (int*)smem;
    char* Ab = smem + 9216;
    float* bsh = (float*)(smem + 50176);
    _Float16* st = (_Float16*)smem;

    int t = threadIdx.x;
    int bid = blockIdx.x;
    {   // bijective XCD-chunked remap (nwg=500: q=62, r=4)
        int xcd = bid & 7, idx = bid >> 3;
        bid = (xcd < 4) ? (xcd * 63 + idx) : (252 + (xcd - 4) * 62 + idx);
    }
    int b = bid / 250;
    int s0 = (bid % 250) * 256;

    int wv = t >> 6, lane = t & 63;
    int n31 = lane & 31, kg = lane >> 5;

    // gll source offsets (fixed across taps): chunk k = wv + 8*i (18 chunks/block)
    int goff[3];
#pragma unroll
    for (int i = 0; i < 3; i++) {
        int k = wv + 8 * i;
        if (k < 18) {
            int u = k * 64 + lane;
            int row = u % 96, blk = u / 96;
            goff[i] = row * 192 + (blk >> 1) * 32 + (blk & 1) * 16;
        }
    }
    // issue tap-0 A stage into buf 0 (drained by the barrier below)
    {
        const char* src = (const char*)wf;
#pragma unroll
        for (int i = 0; i < 3; i++) {
            int k = wv + 8 * i;
            if (k < 18) gll16(src + goff[i], Ab + k * 1024);
        }
    }

    // adh[kd*3+kh][nl] = wrapped (d,h) byte offset for s-local nl (256 entries)
    if (t < 256) {
        int s = s0 + t;
        int d = s / 1600, rr = s - d * 1600;
        int h = rr / 40;
#pragma unroll
        for (int kd = 0; kd < 3; kd++) {
            int dd = d + kd - 1; if (dd < 0) dd += 40; else if (dd >= 40) dd -= 40;
#pragma unroll
            for (int kh = 0; kh < 3; kh++) {
                int hh = h + kh - 1; if (hh < 0) hh += 40; else if (hh >= 40) hh -= 40;
                adh[(kd * 3 + kh) * 256 + t] = dd * 307200 + hh * 7680;
            }
        }
    }
    if (t < 96) bsh[t] = bias[t];

    // per-lane w for its single B-row
    int r0s = s0 + wv * 32 + n31;
    int w0 = r0s % 40;
    __syncthreads();   // adh ready AND tap-0 A landed (barrier drains vmcnt)

    const char* inb = (const char*)(in_t + (size_t)b * 64000 * 96) + kg * 16;

    floatx16 acc[3];
#pragma unroll
    for (int mt = 0; mt < 3; mt++)
#pragma unroll
        for (int r = 0; r < 16; r++) acc[mt][r] = 0.f;

    for (int tap = 0; tap < 27; tap++) {
        int cur = tap & 1;
        if (tap < 26) {   // prefetch next tap's A straight into the other buffer
            const char* src = (const char*)wf + (tap + 1) * 18432;
            char* dstb = Ab + (cur ^ 1) * 18432;
#pragma unroll
            for (int i = 0; i < 3; i++) {
                int k = wv + 8 * i;
                if (k < 18) gll16(src + goff[i], dstb + k * 1024);
            }
        }
        int kdh = tap / 3, kw = tap - kdh * 3;
        int a0 = adh[kdh * 256 + wv * 32 + n31];
        int ww0 = w0 + kw - 1; if (ww0 < 0) ww0 += 40; else if (ww0 >= 40) ww0 -= 40;
        const char* pb0 = inb + a0 + ww0 * 192;
        const char* Ac = Ab + cur * 18432 + kg * 1536 + n31 * 16;
#pragma unroll
        for (int j = 0; j < 6; j++) {
            half8 b0 = *(const half8*)(pb0 + j * 32);
            const char* Aj = Ac + j * 3072;
            half8 a0f = *(const half8*)(Aj);
            half8 a1f = *(const half8*)(Aj + 512);
            half8 a2f = *(const half8*)(Aj + 1024);
            acc[0] = __builtin_amdgcn_mfma_f32_32x32x16_f16(a0f, b0, acc[0], 0, 0, 0);
            acc[1] = __builtin_amdgcn_mfma_f32_32x32x16_f16(a1f, b0, acc[1], 0, 0, 0);
            acc[2] = __builtin_amdgcn_mfma_f32_32x32x16_f16(a2f, b0, acc[2], 0, 0, 0);
        }
        __syncthreads();   // next-tap A landed; buffers swap
    }

    // epilogue: padded transpose (st overlays adh/Ab only; bsh is outside)
#pragma unroll
    for (int mt = 0; mt < 3; mt++)
#pragma unroll
        for (int r = 0; r < 16; r++) {
            int m = mt * 32 + (r & 3) + 8 * (r >> 2) + 4 * kg;
            int sl = wv * 32 + n31;
            st[sl * 98 + m] = (_Float16)(acc[mt][r] + bsh[m]);
        }
    __syncthreads();

    unsigned int* dst = (unsigned int*)(c3 + ((size_t)(b * 64000 + s0)) * 96);
    for (int i = t; i < 12288; i += 512) {
        int row = i / 48, sg = i % 48;
        dst[i] = *(const unsigned int*)&st[row * 98 + sg * 2];
    }
}

// ---------------- per-(b,c) stats over f16 [b][s][96]: atomic partial sums ----------------
__global__ __launch_bounds__(192) void k_stats_sc(const _Float16* __restrict__ in,
                                                  float* __restrict__ raw) {   // [192][2]
    __shared__ float red_s[16][96], red_q[16][96];
    int bid = blockIdx.x;            // 100 blocks: b = bid/50, chunk of 1280 s
    int b = bid / 50, ch = bid % 50;
    int t = threadIdx.x;
    int sp = t / 12, cs = t % 12;
    const uint4* base = (const uint4*)(in + ((size_t)(b * 64000 + ch * 1280)) * 96);
    float s8[8], q8[8];
#pragma unroll
    for (int e = 0; e < 8; e++) { s8[e] = 0.f; q8[e] = 0.f; }
    for (int i = 0; i < 80; i++) {
        uint4 v = base[(sp + i * 16) * 12 + cs];
        half8 h = __builtin_bit_cast(half8, v);
#pragma unroll
        for (int e = 0; e < 8; e++) { float f = (float)h[e]; s8[e] += f; q8[e] += f * f; }
    }
#pragma unroll
    for (int e = 0; e < 8; e++) { red_s[sp][cs * 8 + e] = s8[e]; red_q[sp][cs * 8 + e] = q8[e]; }
    __syncthreads();
    if (t < 96) {
        float S = 0.f, Q = 0.f;
        for (int k = 0; k < 16; k++) { S += red_s[k][t]; Q += red_q[k][t]; }
        atomicAdd(&raw[(b * 96 + t) * 2], S);
        atomicAdd(&raw[(b * 96 + t) * 2 + 1], Q);
    }
}

// ---------------- norm + exact gelu on f16 [b][s][96], in-place; finalize fused ----------------
__global__ __launch_bounds__(256) void k_ng16(_Float16* __restrict__ x, const float* __restrict__ raw) {
    __shared__ float2 sfs[192];
    int t = threadIdx.x, bid = blockIdx.x;
    if (t < 192) {
        float S = raw[t * 2], Q = raw[t * 2 + 1];
        float mu = S * (1.f / 64000.f);
        float var = Q * (1.f / 64000.f) - mu * mu;
        sfs[t] = make_float2(mu, rsqrtf(var + 1e-5f));
    }
    __syncthreads();
    uint4* p = (uint4*)x;
#pragma unroll
    for (int k = 0; k < 4; k++) {
        int i = bid * 1024 + k * 256 + t;      // uint4 index, 1,536,000 total
        int e0 = i * 8;
        int b = e0 / 6144000;
        int c0 = e0 % 96;
        const float2* sp = &sfs[b * 96 + c0];
        uint4 v = p[i];
        half8 h = __builtin_bit_cast(half8, v);
        _Float16 o[8];
#pragma unroll
        for (int e = 0; e < 8; e++) {
            float2 st = sp[e];
            float u = ((float)h[e] - st.x) * st.y;
            o[e] = (_Float16)(0.5f * u * (1.f + erff(u * 0.70710678118654752f)));
        }
        p[i] = *(uint4*)o;
    }
}

// ---------------- 96x96 f16 MFMA GEMM on [b][s][96]; MODE 1: sigmoid * x epilogue ----------------
template <int MODE>
__global__ __launch_bounds__(256) void k_gemm96(const _Float16* __restrict__ in,
                                                const _Float16* __restrict__ w,   // [96][96]
                                                const float* __restrict__ bias,
                                                const float* __restrict__ xg,     // [b][c][s] f32 (MODE 1)
                                                _Float16* __restrict__ outp) {
    __shared__ _Float16 un[12544];   // union: W (9216) | out staging 128 x 98
    __shared__ float bias_s[96];
    int t = threadIdx.x, bid = blockIdx.x;
    { int xcd = bid & 7; bid = xcd * 125 + (bid >> 3); }   // chain conv3's XCD map
    int b = bid / 500, s0 = (bid % 500) * 128;
    for (int i = t; i < 1152; i += 256) ((uint4*)un)[i] = ((const uint4*)w)[i];
    if (t < 96) bias_s[t] = bias[t];
    __syncthreads();

    int ws = t >> 6, lane = t & 63;
    int n = lane & 31, kg = lane >> 5;
    int p = ws * 32 + n;
    const uint4* brow = (const uint4*)(in + ((size_t)(b * 64000 + s0 + p)) * 96);
    uint4 bf[6];
#pragma unroll
    for (int kc = 0; kc < 6; kc++) bf[kc] = brow[kc * 2 + kg];

    floatx16 acc[3];
#pragma unroll
    for (int mt = 0; mt < 3; mt++)
#pragma unroll
        for (int r = 0; r < 16; r++) acc[mt][r] = 0.f;
#pragma unroll
    for (int kc = 0; kc < 6; kc++) {
        half8 bfh = __builtin_bit_cast(half8, bf[kc]);
#pragma unroll
        for (int mt = 0; mt < 3; mt++) {
            uint4 au = *(const uint4*)&un[(mt * 32 + n) * 96 + kc * 16 + kg * 8];
            acc[mt] = __builtin_amdgcn_mfma_f32_32x32x16_f16(__builtin_bit_cast(half8, au), bfh, acc[mt], 0, 0, 0);
        }
    }
    __syncthreads();   // done reading W; un becomes output staging

#pragma unroll
    for (int mt = 0; mt < 3; mt++)
#pragma unroll
        for (int r = 0; r < 16; r++) {
            int m = mt * 32 + (r & 3) + 8 * (r >> 2) + 4 * kg;
            int sl = ws * 32 + n;
            float v = acc[mt][r] + bias_s[m];
            if (MODE == 1) {
                v = 1.f / (1.f + __expf(-v));
                v *= xg[((size_t)(b * 96 + m)) * 64000 + s0 + sl];
            }
            un[sl * 98 + m] = (_Float16)v;
        }
    __syncthreads();

    unsigned int* dst = (unsigned int*)(outp + ((size_t)(b * 64000 + s0)) * 96);
    for (int i = t; i < 6144; i += 256) {
        int row = i / 48, sg = i % 48;
        dst[i] = *(const unsigned int*)&un[row * 98 + sg * 2];
    }
}

// ---------------- qkv GEMM (ONCE): qA[b][s][288] f16, natural s-order ----------------
__global__ __launch_bounds__(256) void k_qkv(const _Float16* __restrict__ xt,
                                             const _Float16* __restrict__ wq,  // [288][96]
                                             const float* __restrict__ qb,
                                             _Float16* __restrict__ qA) {
    __shared__ _Float16 smem[27648];   // union: A (288x96) then epi (64 x 296)
    __shared__ float bias_s[288];
    int t = threadIdx.x;
    int bid = blockIdx.x;
    { int xcd = bid & 7; bid = xcd * 125 + (bid >> 3); }   // chain conv3's XCD map
    int b = bid / 500;
    int s0 = (bid % 500) * 128;

    for (int i = t; i < 3456; i += 256) ((uint4*)smem)[i] = ((const uint4*)wq)[i];
    for (int i = t; i < 288; i += 256) bias_s[i] = qb[i];
    __syncthreads();

    int ws = t >> 6, lane = t & 63;
    int n = lane & 31, kg = lane >> 5;
    int p = ws * 32 + n;

    const uint4* brow = (const uint4*)(xt + ((size_t)(b * 64000 + s0 + p)) * 96);
    uint4 bf[6];
#pragma unroll
    for (int kc = 0; kc < 6; kc++) bf[kc] = brow[kc * 2 + kg];

    floatx16 acc[9];
#pragma unroll
    for (int mt = 0; mt < 9; mt++)
#pragma unroll
        for (int r = 0; r < 16; r++) acc[mt][r] = 0.f;

#pragma unroll
    for (int kc = 0; kc < 6; kc++) {
        half8 bfh = __builtin_bit_cast(half8, bf[kc]);
#pragma unroll
        for (int mt = 0; mt < 9; mt++) {
            uint4 au = *(const uint4*)&smem[(mt * 32 + n) * 96 + kc * 16 + kg * 8];
            acc[mt] = __builtin_amdgcn_mfma_f32_32x32x16_f16(__builtin_bit_cast(half8, au), bfh, acc[mt], 0, 0, 0);
        }
    }

    const float scale = 0.20412414523193154f;
    for (int q = 0; q < 2; q++) {
        __syncthreads();
        if ((ws >> 1) == q) {
            int pl = (ws & 1) * 32 + n;
#pragma unroll
            for (int mt = 0; mt < 9; mt++)
#pragma unroll
                for (int g = 0; g < 4; g++) {
                    int m0 = mt * 32 + g * 8 + kg * 4;
                    _Float16 tm[4];
#pragma unroll
                    for (int j = 0; j < 4; j++) {
                        float v = acc[mt][g * 4 + j] + bias_s[m0 + j];
                        if (m0 + j < 96) v *= scale;
                        tm[j] = (_Float16)v;
                    }
                    *(uint2*)&smem[pl * 296 + m0] = *(uint2*)tm;
                }
        }
        __syncthreads();
        for (int idx = t; idx < 2304; idx += 256) {
            int pl = idx / 36, seg = idx % 36;
            int s = s0 + q * 64 + pl;
            uint4 v = *(const uint4*)&smem[pl * 296 + seg * 8];
            *(uint4*)&qA[((size_t)(b * 64000 + s)) * 288 + seg * 8] = v;
        }
    }
}

// ---------------- fused axial attention: softmax + PV, sum into osum[b][s][96] ----------------
// block=320: 2 lines x (4 heads x 40 queries), one query/thread.
template <int AXIS, bool ACC>
__global__ __launch_bounds__(320, 3) void k_attn(const _Float16* __restrict__ qA,
                                                 _Float16* __restrict__ osum) {
    __shared__ _Float16 kk[8352];     // k: [line][key][96]; then out staging [line][l][104]
    __shared__ _Float16 vT[7744];     // plane lh=line*4+head, stride 968: [hd][40 keys]
    int t = threadIdx.x;
    int bid = blockIdx.x;
    bid = (bid & 7) * 200 + (bid >> 3);   // bijective XCD chunking (1600%8==0)
    int b = bid / 800;
    int r0 = (bid % 800) * 2;

    auto smap = [&](int r, int l) -> int {
        if (AXIS == 0) return l * 1600 + r;
        else if (AXIS == 1) { int d = r / 40, w = r % 40; return d * 1600 + l * 40 + w; }
        else return r * 40 + l;
    };
    const uint4* src = (const uint4*)qA;
    for (int i = t; i < 960; i += 320) {
        int line = i / 480, key = (i % 480) / 12, seg = i % 12;
        int row = b * 64000 + smap(r0 + line, key);
        ((uint4*)kk)[i] = src[(size_t)row * 36 + 12 + seg];
    }
    for (int i = t; i < 960; i += 320) {
        int line = i / 480, key = (i % 480) / 12, seg = i % 12;
        int row = b * 64000 + smap(r0 + line, key);
        uint4 v = src[(size_t)row * 36 + 24 + seg];
        _Float16 tmp[8];
        *(uint4*)tmp = v;
#pragma unroll
        for (int e = 0; e < 8; e++) {
            int hdg = seg * 8 + e;
            vT[(line * 4 + hdg / 24) * 968 + (hdg % 24) * 40 + key] = tmp[e];
        }
    }

    int line = t / 160, head = (t % 160) / 40, ql = t % 40;
    int rr = r0 + line;
    unsigned int qu[12];
    {
        const uint4* qp = (const uint4*)(qA + ((size_t)(b * 64000 + smap(rr, ql))) * 288 + head * 24);
#pragma unroll
        for (int j = 0; j < 3; j++) *(uint4*)&qu[j * 4] = qp[j];
    }
    __syncthreads();

    float s[40];
    const uint4* kbase = (const uint4*)kk + line * 480 + head * 3;
#pragma unroll 4
    for (int key = 0; key < 40; key++) {
        unsigned int kku[12];
#pragma unroll
        for (int j = 0; j < 3; j++) *(uint4*)&kku[j * 4] = kbase[key * 12 + j];
        float a = 0.f;
#pragma unroll
        for (int i = 0; i < 12; i++) a = fdot2(kku[i], qu[i], a);
        s[key] = a;
    }

    float mx = -1e30f;
#pragma unroll
    for (int i = 0; i < 40; i++) mx = fmaxf(mx, s[i]);
    float sum = 0.f;
#pragma unroll
    for (int i = 0; i < 40; i++) { s[i] = __expf(s[i] - mx); sum += s[i]; }
    float inv = 1.f / sum;

    unsigned int pw[20];
#pragma unroll
    for (int i = 0; i < 20; i++) {
        half2 a = { (_Float16)(s[2 * i] * inv), (_Float16)(s[2 * i + 1] * inv) };
        pw[i] = __builtin_bit_cast(unsigned int, a);
    }

    __syncthreads();   // kk becomes output staging

    float o[24];
    const uint4* vbase = (const uint4*)vT + (line * 4 + head) * 121;
#pragma unroll 2
    for (int hd = 0; hd < 24; hd++) {
        unsigned int vv[20];
#pragma unroll
        for (int j = 0; j < 5; j++) *(uint4*)&vv[j * 4] = vbase[hd * 5 + j];
        float a = 0.f;
#pragma unroll
        for (int i = 0; i < 20; i++) a = fdot2(vv[i], pw[i], a);
        o[hd] = a;
    }

    {
        _Float16 tm[24];
#pragma unroll
        for (int j = 0; j < 24; j++) tm[j] = (_Float16)o[j];
        _Float16* dA = &kk[(line * 40 + ql) * 104 + head * 24];
#pragma unroll
        for (int j = 0; j < 3; j++) ((uint4*)dA)[j] = ((uint4*)tm)[j];
    }
    __syncthreads();

    // flush 80 rows x 96 f16 to osum[smap(r,l)] (192B rows; contiguous for AXIS 2)
    uint4* dst = (uint4*)osum;
    for (int i = t; i < 960; i += 320) {
        int row = i / 12, seg = i % 12;
        int s2 = smap(r0 + row / 40, row % 40);
        size_t di = ((size_t)(b * 64000 + s2)) * 12 + seg;
        uint4 v = *(const uint4*)&kk[row * 104 + seg * 8];
        if (ACC) {
            half8 a = __builtin_bit_cast(half8, dst[di]);
            half8 c = __builtin_bit_cast(half8, v);
            dst[di] = __builtin_bit_cast(uint4, a + c);
        } else {
            dst[di] = v;
        }
    }
}

// ---------------- proj GEMM: out[b][c][s] = proj_w @ osum[b][s][96] + pb ----------------
__global__ __launch_bounds__(256) void k_proj(const _Float16* __restrict__ osum,
                                              const _Float16* __restrict__ wp,  // [96][96]
                                              const float* __restrict__ pb,
                                              float* __restrict__ out) {
    __shared__ _Float16 A[9216];
    __shared__ float bias_s[96];
    int t = threadIdx.x;
    int bid = blockIdx.x;
    int b = bid / 500;
    int s0 = (bid % 500) * 128;
    for (int i = t; i < 1152; i += 256) ((uint4*)A)[i] = ((const uint4*)wp)[i];
    if (t < 96) bias_s[t] = pb[t];
    __syncthreads();

    int ws = t >> 6, lane = t & 63;
    int n = lane & 31, kg = lane >> 5;
    int s = s0 + ws * 32 + n;

    const uint4* brow = (const uint4*)(osum + ((size_t)(b * 64000 + s0 + ws * 32 + n)) * 96);
    uint4 bf[6];
#pragma unroll
    for (int kc = 0; kc < 6; kc++) bf[kc] = brow[kc * 2 + kg];

    floatx16 acc[3];
#pragma unroll
    for (int mt = 0; mt < 3; mt++)
#pragma unroll
        for (int r = 0; r < 16; r++) acc[mt][r] = 0.f;

#pragma unroll
    for (int kc = 0; kc < 6; kc++) {
        half8 bfh = __builtin_bit_cast(half8, bf[kc]);
#pragma unroll
        for (int mt = 0; mt < 3; mt++) {
            uint4 au = *(const uint4*)&A[(mt * 32 + n) * 96 + kc * 16 + kg * 8];
            acc[mt] = __builtin_amdgcn_mfma_f32_32x32x16_f16(__builtin_bit_cast(half8, au), bfh, acc[mt], 0, 0, 0);
        }
    }

#pragma unroll
    for (int mt = 0; mt < 3; mt++)
#pragma unroll
        for (int r = 0; r < 16; r++) {
            int m = mt * 32 + (r & 3) + 8 * (r >> 2) + 4 * kg;
            out[((size_t)(b * 96 + m)) * 64000 + s] = acc[mt][r] + bias_s[m];
        }
}

extern "C" void kernel_launch(void* const* d_in, const int* in_sizes, int n_in,
                              void* d_out, int out_size, void* d_ws, size_t ws_size,
                              hipStream_t stream) {
    const float* x      = (const float*)d_in[0];
    const float* pos    = (const float*)d_in[1];
    const float* qkv_w  = (const float*)d_in[2];
    const float* qkv_b  = (const float*)d_in[3];
    const float* lp1_w  = (const float*)d_in[4];
    const float* lp1_b  = (const float*)d_in[5];
    const float* lp2_w  = (const float*)d_in[6];
    const float* lp2_b  = (const float*)d_in[7];
    const float* mod1_w = (const float*)d_in[8];
    const float* mod1_b = (const float*)d_in[9];
    const float* mod2_w = (const float*)d_in[10];
    const float* mod2_b = (const float*)d_in[11];
    // d_in[12..16]: pa_w, pa_b, R6_d, R6_h, R6_w — provably no-ops (see header)
    const float* proj_w = (const float*)d_in[17];
    const float* proj_b = (const float*)d_in[18];
    float* out = (float*)d_out;
    float* ws = (float*)d_ws;

    // f16 buffers (sizes in f32-float units of ws):
    _Float16* bufA = (_Float16*)ws;                        // 12.288M f16: c3/B0 -> xm
    _Float16* bufB = (_Float16*)(ws + 6144000);            // 12.288M f16: C2/D -> osum
    _Float16* qA   = (_Float16*)(ws + 12288000);           // 36.864M f16
    _Float16* in_t = qA;                                   // pos f16 [s][c], dead before qkv
    _Float16* wf   = (_Float16*)(ws + 30720000);           // 248,832 f16
    _Float16* wq   = (_Float16*)(ws + 30844416);           // 27,648 f16
    _Float16* wpj  = (_Float16*)(ws + 30858240);           // 9,216 f16
    _Float16* wfold= (_Float16*)(ws + 30862848);           // 9,216 f16
    _Float16* wm2  = (_Float16*)(ws + 30867456);           // 9,216 f16
    float* bfold   = ws + 30872064;                        // 96 f32
    float* raw     = ws + 30872160;                        // 768 f32 (raw0 | raw1)
    float* raw0 = raw, *raw1 = raw + 384;

    k_cvt_in<<<2016, 256, 0, stream>>>(pos, in_t);
    k_cvt_w<<<972, 256, 0, stream>>>(lp1_w, wf, raw);     // block 0 zeroes raw
    k_fold<<<36, 256, 0, stream>>>(lp2_w, lp2_b, mod1_w, mod1_b, wfold, bfold);
    k_cvt_f16<<<36, 256, 0, stream>>>(mod2_w, wm2, 9216);
    k_cvt_f16<<<108, 256, 0, stream>>>(qkv_w, wq, 27648);
    k_cvt_f16<<<36, 256, 0, stream>>>(proj_w, wpj, 9216);

    // c3 = conv3(pos)  [f16, [b][s][96]]
    k_conv3_v9<<<500, 512, 0, stream>>>(in_t, wf, lp1_b, bufA);
    // B0 = gelu(IN(c3)) in-place (finalize fused into ng16)
    k_stats_sc<<<100, 192, 0, stream>>>(bufA, raw0);
    k_ng16<<<1500, 256, 0, stream>>>(bufA, raw0);
    // C2 = W' @ B0 + b'   (folded lp2 -> mod1)
    k_gemm96<0><<<1000, 256, 0, stream>>>(bufA, wfold, bfold, nullptr, bufB);
    // D = gelu(IN(C2)) in-place
    k_stats_sc<<<100, 192, 0, stream>>>(bufB, raw1);
    k_ng16<<<1500, 256, 0, stream>>>(bufB, raw1);
    // xm = x * sigmoid(mod2 @ D + b)   [f16 [b][s][96], into bufA (B0 dead)]
    k_gemm96<1><<<1000, 256, 0, stream>>>(bufB, wm2, mod2_b, x, bufA);

    // qkv ONCE (s-order); qA overwrites in_t (dead)
    k_qkv<<<1000, 256, 0, stream>>>(bufA, wq, qkv_b, qA);
    // attention: axis 2 writes osum (contiguous), axes 0/1 accumulate (192B-row RMW)
    k_attn<2, false><<<1600, 320, 0, stream>>>(qA, bufB);
    k_attn<0, true ><<<1600, 320, 0, stream>>>(qA, bufB);
    k_attn<1, true ><<<1600, 320, 0, stream>>>(qA, bufB);

    // out = proj(osum)
    k_proj<<<1000, 256, 0, stream>>>(bufB, wpj, proj_b, out);
}

// Round 12
// 674.951 us; speedup vs baseline: 1.0088x; 1.0088x over previous
//
#include <hip/hip_runtime.h>

// Problem constants: B=2, C=96, D=H=W=40, S=64000, NH=4, HD=24, L=40
// Exact simplifications vs reference:
//  - pos_attn branch dropped (softmax row-shift invariance)
//  - R6 rotations dropped (R orthogonal; (Rq).(Rk) = q.k; v unrotated)
//  - mod1@ (lp2@B + b2) + b1 folded to W'@B + b'  (W' = mod1@lp2, exact)
// conv3 history: r7 XCD swizzle; r13 A via global_load_lds dbuf (98us);
// r16(v8b) compact tables (90us, total 649.6 BEST). r17(v9) 8-wave blocks
// REGRESSED (122us at 39% occupancy): fewer MFMAs/barrier + less per-wave
// MLP beat the occupancy gain. conv3 frozen at v8b; declared practical floor.
// r18: rest-pipeline round. (a) attn 4 lines/block: axis-0/1 K/V gather rows
// become 768B-contiguous quads (2x line efficiency on the random-HBM gather);
// (b) stats_sc grid 100->500 (full-GPU reduction). conv3/gemm/qkv untouched.

typedef __attribute__((ext_vector_type(8))) _Float16 half8;
typedef __attribute__((ext_vector_type(2))) _Float16 half2;
typedef __attribute__((ext_vector_type(16))) float floatx16;

static __device__ __forceinline__ half2 h2(unsigned int u) {
    return __builtin_bit_cast(half2, u);
}
static __device__ __forceinline__ float fdot2(unsigned int a, unsigned int b, float c) {
    return __builtin_amdgcn_fdot2(h2(a), h2(b), c, false);
}

typedef __attribute__((address_space(1))) const void gas_t;
typedef __attribute__((address_space(3))) void las_t;
static __device__ __forceinline__ void gll16(const void* g, void* l) {
    __builtin_amdgcn_global_load_lds((gas_t*)g, (las_t*)l, 16, 0, 0);
}

// ---------------- prep: pos fp32 [b][c][s] -> f16 [b][s][c], XCD-aligned ----------------
__global__ __launch_bounds__(256) void k_cvt_in(const float* __restrict__ pos,
                                                _Float16* __restrict__ in_t) {
    __shared__ _Float16 lds[64][97];
    int bid = blockIdx.x;
    int xcd = bid & 7, k = bid >> 3;      // k 0..251
    int L;
    if (xcd < 4) L = xcd * 63 + (k >> 2);
    else { if (k >= 248) return; L = 252 + (xcd - 4) * 62 + (k >> 2); }
    int q = k & 3;
    int b = L / 250;
    int s0 = (L % 250) * 256 + q * 64;
    int t = threadIdx.x;
    for (int i = t; i < 6144; i += 256) {
        int c = i / 64, sl = i % 64;
        lds[sl][c] = (_Float16)pos[(b * 96 + c) * 64000 + s0 + sl];
    }
    __syncthreads();
    _Float16* outp = in_t + ((size_t)b * 64000 + s0) * 96;
    for (int i = t; i < 6144; i += 256) {
        int sl = i / 96, c = i % 96;
        outp[i] = lds[sl][c];
    }
}

// ---------------- prep: lp1_w [o][c][tap] -> f16 wf [tap][o][c]; block 0 zeroes raw ----------------
__global__ void k_cvt_w(const float* __restrict__ w, _Float16* __restrict__ wf,
                        float* __restrict__ raw) {
    int i = blockIdx.x * 256 + threadIdx.x;
    if (i < 248832) {
        int c = i % 96, m = (i / 96) % 96, tap = i / 9216;
        wf[i] = (_Float16)w[(m * 96 + c) * 27 + tap];
    }
    if (blockIdx.x == 0) {
        for (int u = threadIdx.x; u < 768; u += 256) raw[u] = 0.f;
    }
}

// ---------------- prep: f32 -> f16 straight copy ----------------
__global__ void k_cvt_f16(const float* __restrict__ w, _Float16* __restrict__ o, int n) {
    int i = blockIdx.x * 256 + threadIdx.x;
    if (i < n) o[i] = (_Float16)w[i];
}

// ---------------- prep: W' = mod1_w @ lp2_w (f16), b' = mod1_w @ lp2_b + mod1_b ----------------
__global__ __launch_bounds__(256) void k_fold(const float* __restrict__ lp2_w,
                                              const float* __restrict__ lp2_b,
                                              const float* __restrict__ mod1_w,
                                              const float* __restrict__ mod1_b,
                                              _Float16* __restrict__ wfold,
                                              float* __restrict__ bfold) {
    int i = blockIdx.x * 256 + threadIdx.x;   // grid 36 -> 9216 outputs
    if (i < 9216) {
        int o = i / 96, c = i % 96;
        float a = 0.f;
        for (int k = 0; k < 96; k++) a += mod1_w[o * 96 + k] * lp2_w[k * 96 + c];
        wfold[i] = (_Float16)a;
    }
    if (blockIdx.x == 0 && threadIdx.x < 96) {
        int o = threadIdx.x;
        float a = mod1_b[o];
        for (int k = 0; k < 96; k++) a += mod1_w[o * 96 + k] * lp2_b[k];
        bfold[o] = a;
    }
}

// ---------------- conv 3x3x3 circular: v8b (frozen best: 90us) ----------------
__global__ __launch_bounds__(256) void k_conv3_v8(const _Float16* __restrict__ in_t,
                                                  const _Float16* __restrict__ wf,  // [tap][m][c]
                                                  const float* __restrict__ bias,
                                                  _Float16* __restrict__ c3) {
    // smem: adh int[9][256] @0 (9216) | A dbuf 2x18432 @9216 (ends 46080)
    //       | bsh float[96] @50176 (384, OUTSIDE st range). st f16[256*98] @0.
    __shared__ __align__(16) char smem[50560];
    int* adh = (int*)smem;
    char* Ab = smem + 9216;
    float* bsh = (float*)(smem + 50176);
    _Float16* st = (_Float16*)smem;

    int t = threadIdx.x;
    int bid = blockIdx.x;
    {   // bijective XCD-chunked remap (nwg=500: q=62, r=4)
        int xcd = bid & 7, idx = bid >> 3;
        bid = (xcd < 4) ? (xcd * 63 + idx) : (252 + (xcd - 4) * 62 + idx);
    }
    int b = bid / 250;
    int s0 = (bid % 250) * 256;

    int wv = t >> 6, lane = t & 63;
    int n31 = lane & 31, kg = lane >> 5;

    int goff[5];
#pragma unroll
    for (int i = 0; i < 5; i++) {
        int k = wv + 4 * i;
        if (k < 18) {
            int u = k * 64 + lane;
            int row = u % 96, blk = u / 96;
            goff[i] = row * 192 + (blk >> 1) * 32 + (blk & 1) * 16;
        }
    }
    {
        const char* src = (const char*)wf;
#pragma unroll
        for (int i = 0; i < 5; i++) {
            int k = wv + 4 * i;
            if (k < 18) gll16(src + goff[i], Ab + k * 1024);
        }
    }

    {
        int s = s0 + t;
        int d = s / 1600, rr = s - d * 1600;
        int h = rr / 40;
#pragma unroll
        for (int kd = 0; kd < 3; kd++) {
            int dd = d + kd - 1; if (dd < 0) dd += 40; else if (dd >= 40) dd -= 40;
#pragma unroll
            for (int kh = 0; kh < 3; kh++) {
                int hh = h + kh - 1; if (hh < 0) hh += 40; else if (hh >= 40) hh -= 40;
                adh[(kd * 3 + kh) * 256 + t] = dd * 307200 + hh * 7680;
            }
        }
    }
    if (t < 96) bsh[t] = bias[t];

    int r0s = s0 + wv * 64 + n31;
    int w0 = r0s % 40;
    int w1 = (r0s + 32) % 40;
    __syncthreads();   // adh ready AND tap-0 A landed

    const char* inb = (const char*)(in_t + (size_t)b * 64000 * 96) + kg * 16;

    floatx16 acc[3][2];
#pragma unroll
    for (int mt = 0; mt < 3; mt++)
#pragma unroll
        for (int nt = 0; nt < 2; nt++)
#pragma unroll
            for (int r = 0; r < 16; r++) acc[mt][nt][r] = 0.f;

    for (int tap = 0; tap < 27; tap++) {
        int cur = tap & 1;
        if (tap < 26) {
            const char* src = (const char*)wf + (tap + 1) * 18432;
            char* dstb = Ab + (cur ^ 1) * 18432;
#pragma unroll
            for (int i = 0; i < 5; i++) {
                int k = wv + 4 * i;
                if (k < 18) gll16(src + goff[i], dstb + k * 1024);
            }
        }
        int kdh = tap / 3, kw = tap - kdh * 3;
        int a0 = adh[kdh * 256 + wv * 64 + n31];
        int a1 = adh[kdh * 256 + wv * 64 + 32 + n31];
        int ww0 = w0 + kw - 1; if (ww0 < 0) ww0 += 40; else if (ww0 >= 40) ww0 -= 40;
        int ww1 = w1 + kw - 1; if (ww1 < 0) ww1 += 40; else if (ww1 >= 40) ww1 -= 40;
        const char* pb0 = inb + a0 + ww0 * 192;
        const char* pb1 = inb + a1 + ww1 * 192;
        const char* Ac = Ab + cur * 18432 + kg * 1536 + n31 * 16;
#pragma unroll
        for (int j = 0; j < 6; j++) {
            half8 b0 = *(const half8*)(pb0 + j * 32);
            half8 b1 = *(const half8*)(pb1 + j * 32);
            const char* Aj = Ac + j * 3072;
            half8 a0f = *(const half8*)(Aj);
            half8 a1f = *(const half8*)(Aj + 512);
            half8 a2f = *(const half8*)(Aj + 1024);
            acc[0][0] = __builtin_amdgcn_mfma_f32_32x32x16_f16(a0f, b0, acc[0][0], 0, 0, 0);
            acc[0][1] = __builtin_amdgcn_mfma_f32_32x32x16_f16(a0f, b1, acc[0][1], 0, 0, 0);
            acc[1][0] = __builtin_amdgcn_mfma_f32_32x32x16_f16(a1f, b0, acc[1][0], 0, 0, 0);
            acc[1][1] = __builtin_amdgcn_mfma_f32_32x32x16_f16(a1f, b1, acc[1][1], 0, 0, 0);
            acc[2][0] = __builtin_amdgcn_mfma_f32_32x32x16_f16(a2f, b0, acc[2][0], 0, 0, 0);
            acc[2][1] = __builtin_amdgcn_mfma_f32_32x32x16_f16(a2f, b1, acc[2][1], 0, 0, 0);
        }
        __syncthreads();
    }

#pragma unroll
    for (int mt = 0; mt < 3; mt++)
#pragma unroll
        for (int nt = 0; nt < 2; nt++)
#pragma unroll
            for (int r = 0; r < 16; r++) {
                int m = mt * 32 + (r & 3) + 8 * (r >> 2) + 4 * kg;
                int sl = wv * 64 + nt * 32 + n31;
                st[sl * 98 + m] = (_Float16)(acc[mt][nt][r] + bsh[m]);
            }
    __syncthreads();

    unsigned int* dst = (unsigned int*)(c3 + ((size_t)(b * 64000 + s0)) * 96);
    for (int i = t; i < 12288; i += 256) {
        int row = i / 48, sg = i % 48;
        dst[i] = *(const unsigned int*)&st[row * 98 + sg * 2];
    }
}

// ---------------- per-(b,c) stats over f16 [b][s][96]: atomic partial sums ----------------
// r18: grid 500 (256-s chunks) — full-GPU reduction (was 100 blocks).
__global__ __launch_bounds__(192) void k_stats_sc(const _Float16* __restrict__ in,
                                                  float* __restrict__ raw) {   // [192][2]
    __shared__ float red_s[16][96], red_q[16][96];
    int bid = blockIdx.x;            // 500 blocks: b = bid/250, chunk of 256 s
    int b = bid / 250, ch = bid % 250;
    int t = threadIdx.x;
    int sp = t / 12, cs = t % 12;
    const uint4* base = (const uint4*)(in + ((size_t)(b * 64000 + ch * 256)) * 96);
    float s8[8], q8[8];
#pragma unroll
    for (int e = 0; e < 8; e++) { s8[e] = 0.f; q8[e] = 0.f; }
#pragma unroll
    for (int i = 0; i < 16; i++) {
        uint4 v = base[(sp + i * 16) * 12 + cs];
        half8 h = __builtin_bit_cast(half8, v);
#pragma unroll
        for (int e = 0; e < 8; e++) { float f = (float)h[e]; s8[e] += f; q8[e] += f * f; }
    }
#pragma unroll
    for (int e = 0; e < 8; e++) { red_s[sp][cs * 8 + e] = s8[e]; red_q[sp][cs * 8 + e] = q8[e]; }
    __syncthreads();
    if (t < 96) {
        float S = 0.f, Q = 0.f;
        for (int k = 0; k < 16; k++) { S += red_s[k][t]; Q += red_q[k][t]; }
        atomicAdd(&raw[(b * 96 + t) * 2], S);
        atomicAdd(&raw[(b * 96 + t) * 2 + 1], Q);
    }
}

// ---------------- norm + exact gelu on f16 [b][s][96], in-place; finalize fused ----------------
__global__ __launch_bounds__(256) void k_ng16(_Float16* __restrict__ x, const float* __restrict__ raw) {
    __shared__ float2 sfs[192];
    int t = threadIdx.x, bid = blockIdx.x;
    if (t < 192) {
        float S = raw[t * 2], Q = raw[t * 2 + 1];
        float mu = S * (1.f / 64000.f);
        float var = Q * (1.f / 64000.f) - mu * mu;
        sfs[t] = make_float2(mu, rsqrtf(var + 1e-5f));
    }
    __syncthreads();
    uint4* p = (uint4*)x;
#pragma unroll
    for (int k = 0; k < 4; k++) {
        int i = bid * 1024 + k * 256 + t;      // uint4 index, 1,536,000 total
        int e0 = i * 8;
        int b = e0 / 6144000;
        int c0 = e0 % 96;
        const float2* sp = &sfs[b * 96 + c0];
        uint4 v = p[i];
        half8 h = __builtin_bit_cast(half8, v);
        _Float16 o[8];
#pragma unroll
        for (int e = 0; e < 8; e++) {
            float2 st = sp[e];
            float u = ((float)h[e] - st.x) * st.y;
            o[e] = (_Float16)(0.5f * u * (1.f + erff(u * 0.70710678118654752f)));
        }
        p[i] = *(uint4*)o;
    }
}

// ---------------- 96x96 f16 MFMA GEMM on [b][s][96]; MODE 1: sigmoid * x epilogue ----------------
template <int MODE>
__global__ __launch_bounds__(256) void k_gemm96(const _Float16* __restrict__ in,
                                                const _Float16* __restrict__ w,   // [96][96]
                                                const float* __restrict__ bias,
                                                const float* __restrict__ xg,     // [b][c][s] f32 (MODE 1)
                                                _Float16* __restrict__ outp) {
    __shared__ _Float16 un[12544];   // union: W (9216) | out staging 128 x 98
    __shared__ float bias_s[96];
    int t = threadIdx.x, bid = blockIdx.x;
    { int xcd = bid & 7; bid = xcd * 125 + (bid >> 3); }   // chain conv3's XCD map
    int b = bid / 500, s0 = (bid % 500) * 128;
    for (int i = t; i < 1152; i += 256) ((uint4*)un)[i] = ((const uint4*)w)[i];
    if (t < 96) bias_s[t] = bias[t];
    __syncthreads();

    int ws = t >> 6, lane = t & 63;
    int n = lane & 31, kg = lane >> 5;
    int p = ws * 32 + n;
    const uint4* brow = (const uint4*)(in + ((size_t)(b * 64000 + s0 + p)) * 96);
    uint4 bf[6];
#pragma unroll
    for (int kc = 0; kc < 6; kc++) bf[kc] = brow[kc * 2 + kg];

    floatx16 acc[3];
#pragma unroll
    for (int mt = 0; mt < 3; mt++)
#pragma unroll
        for (int r = 0; r < 16; r++) acc[mt][r] = 0.f;
#pragma unroll
    for (int kc = 0; kc < 6; kc++) {
        half8 bfh = __builtin_bit_cast(half8, bf[kc]);
#pragma unroll
        for (int mt = 0; mt < 3; mt++) {
            uint4 au = *(const uint4*)&un[(mt * 32 + n) * 96 + kc * 16 + kg * 8];
            acc[mt] = __builtin_amdgcn_mfma_f32_32x32x16_f16(__builtin_bit_cast(half8, au), bfh, acc[mt], 0, 0, 0);
        }
    }
    __syncthreads();   // done reading W; un becomes output staging

#pragma unroll
    for (int mt = 0; mt < 3; mt++)
#pragma unroll
        for (int r = 0; r < 16; r++) {
            int m = mt * 32 + (r & 3) + 8 * (r >> 2) + 4 * kg;
            int sl = ws * 32 + n;
            float v = acc[mt][r] + bias_s[m];
            if (MODE == 1) {
                v = 1.f / (1.f + __expf(-v));
                v *= xg[((size_t)(b * 96 + m)) * 64000 + s0 + sl];
            }
            un[sl * 98 + m] = (_Float16)v;
        }
    __syncthreads();

    unsigned int* dst = (unsigned int*)(outp + ((size_t)(b * 64000 + s0)) * 96);
    for (int i = t; i < 6144; i += 256) {
        int row = i / 48, sg = i % 48;
        dst[i] = *(const unsigned int*)&un[row * 98 + sg * 2];
    }
}

// ---------------- qkv GEMM (ONCE): qA[b][s][288] f16, natural s-order ----------------
__global__ __launch_bounds__(256) void k_qkv(const _Float16* __restrict__ xt,
                                             const _Float16* __restrict__ wq,  // [288][96]
                                             const float* __restrict__ qb,
                                             _Float16* __restrict__ qA) {
    __shared__ _Float16 smem[27648];   // union: A (288x96) then epi (64 x 296)
    __shared__ float bias_s[288];
    int t = threadIdx.x;
    int bid = blockIdx.x;
    { int xcd = bid & 7; bid = xcd * 125 + (bid >> 3); }   // chain conv3's XCD map
    int b = bid / 500;
    int s0 = (bid % 500) * 128;

    for (int i = t; i < 3456; i += 256) ((uint4*)smem)[i] = ((const uint4*)wq)[i];
    for (int i = t; i < 288; i += 256) bias_s[i] = qb[i];
    __syncthreads();

    int ws = t >> 6, lane = t & 63;
    int n = lane & 31, kg = lane >> 5;
    int p = ws * 32 + n;

    const uint4* brow = (const uint4*)(xt + ((size_t)(b * 64000 + s0 + p)) * 96);
    uint4 bf[6];
#pragma unroll
    for (int kc = 0; kc < 6; kc++) bf[kc] = brow[kc * 2 + kg];

    floatx16 acc[9];
#pragma unroll
    for (int mt = 0; mt < 9; mt++)
#pragma unroll
        for (int r = 0; r < 16; r++) acc[mt][r] = 0.f;

#pragma unroll
    for (int kc = 0; kc < 6; kc++) {
        half8 bfh = __builtin_bit_cast(half8, bf[kc]);
#pragma unroll
        for (int mt = 0; mt < 9; mt++) {
            uint4 au = *(const uint4*)&smem[(mt * 32 + n) * 96 + kc * 16 + kg * 8];
            acc[mt] = __builtin_amdgcn_mfma_f32_32x32x16_f16(__builtin_bit_cast(half8, au), bfh, acc[mt], 0, 0, 0);
        }
    }

    const float scale = 0.20412414523193154f;
    for (int q = 0; q < 2; q++) {
        __syncthreads();
        if ((ws >> 1) == q) {
            int pl = (ws & 1) * 32 + n;
#pragma unroll
            for (int mt = 0; mt < 9; mt++)
#pragma unroll
                for (int g = 0; g < 4; g++) {
                    int m0 = mt * 32 + g * 8 + kg * 4;
                    _Float16 tm[4];
#pragma unroll
                    for (int j = 0; j < 4; j++) {
                        float v = acc[mt][g * 4 + j] + bias_s[m0 + j];
                        if (m0 + j < 96) v *= scale;
                        tm[j] = (_Float16)v;
                    }
                    *(uint2*)&smem[pl * 296 + m0] = *(uint2*)tm;
                }
        }
        __syncthreads();
        for (int idx = t; idx < 2304; idx += 256) {
            int pl = idx / 36, seg = idx % 36;
            int s = s0 + q * 64 + pl;
            uint4 v = *(const uint4*)&smem[pl * 296 + seg * 8];
            *(uint4*)&qA[((size_t)(b * 64000 + s)) * 288 + seg * 8] = v;
        }
    }
}

// ---------------- fused axial attention: softmax + PV, sum into osum[b][s][96] ----------------
// r18: 4 lines/block (640 thr, grid 800). Axis-0/1 K/V gathers now read
// 768B-contiguous quads (4 adjacent r) -> 2x line efficiency on random HBM.
template <int AXIS, bool ACC>
__global__ __launch_bounds__(640) void k_attn(const _Float16* __restrict__ qA,
                                              _Float16* __restrict__ osum) {
    __shared__ _Float16 kk[16640];    // k: [line][key][96] (15360); out staging [line][l][104] (16640)
    __shared__ _Float16 vT[15488];    // plane lh=line*4+head, stride 968: [hd][40 keys]
    int t = threadIdx.x;
    int bid = blockIdx.x;
    bid = (bid & 7) * 100 + (bid >> 3);   // bijective XCD chunking (800%8==0)
    int b = bid / 400;
    int r0 = (bid % 400) * 4;

    auto smap = [&](int r, int l) -> int {
        if (AXIS == 0) return l * 1600 + r;
        else if (AXIS == 1) { int d = r / 40, w = r % 40; return d * 1600 + l * 40 + w; }
        else return r * 40 + l;
    };
    const uint4* src = (const uint4*)qA;
    for (int i = t; i < 1920; i += 640) {
        int line = i / 480, key = (i % 480) / 12, seg = i % 12;
        int row = b * 64000 + smap(r0 + line, key);
        ((uint4*)kk)[i] = src[(size_t)row * 36 + 12 + seg];
    }
    for (int i = t; i < 1920; i += 640) {
        int line = i / 480, key = (i % 480) / 12, seg = i % 12;
        int row = b * 64000 + smap(r0 + line, key);
        uint4 v = src[(size_t)row * 36 + 24 + seg];
        _Float16 tmp[8];
        *(uint4*)tmp = v;
#pragma unroll
        for (int e = 0; e < 8; e++) {
            int hdg = seg * 8 + e;
            vT[(line * 4 + hdg / 24) * 968 + (hdg % 24) * 40 + key] = tmp[e];
        }
    }

    int line = t / 160, head = (t % 160) / 40, ql = t % 40;
    int rr = r0 + line;
    unsigned int qu[12];
    {
        const uint4* qp = (const uint4*)(qA + ((size_t)(b * 64000 + smap(rr, ql))) * 288 + head * 24);
#pragma unroll
        for (int j = 0; j < 3; j++) *(uint4*)&qu[j * 4] = qp[j];
    }
    __syncthreads();

    float s[40];
    const uint4* kbase = (const uint4*)kk + line * 480 + head * 3;
#pragma unroll 4
    for (int key = 0; key < 40; key++) {
        unsigned int kku[12];
#pragma unroll
        for (int j = 0; j < 3; j++) *(uint4*)&kku[j * 4] = kbase[key * 12 + j];
        float a = 0.f;
#pragma unroll
        for (int i = 0; i < 12; i++) a = fdot2(kku[i], qu[i], a);
        s[key] = a;
    }

    float mx = -1e30f;
#pragma unroll
    for (int i = 0; i < 40; i++) mx = fmaxf(mx, s[i]);
    float sum = 0.f;
#pragma unroll
    for (int i = 0; i < 40; i++) { s[i] = __expf(s[i] - mx); sum += s[i]; }
    float inv = 1.f / sum;

    unsigned int pw[20];
#pragma unroll
    for (int i = 0; i < 20; i++) {
        half2 a = { (_Float16)(s[2 * i] * inv), (_Float16)(s[2 * i + 1] * inv) };
        pw[i] = __builtin_bit_cast(unsigned int, a);
    }

    __syncthreads();   // kk becomes output staging

    float o[24];
    const uint4* vbase = (const uint4*)vT + (line * 4 + head) * 121;
#pragma unroll 2
    for (int hd = 0; hd < 24; hd++) {
        unsigned int vv[20];
#pragma unroll
        for (int j = 0; j < 5; j++) *(uint4*)&vv[j * 4] = vbase[hd * 5 + j];
        float a = 0.f;
#pragma unroll
        for (int i = 0; i < 20; i++) a = fdot2(vv[i], pw[i], a);
        o[hd] = a;
    }

    {
        _Float16 tm[24];
#pragma unroll
        for (int j = 0; j < 24; j++) tm[j] = (_Float16)o[j];
        _Float16* dA = &kk[(line * 40 + ql) * 104 + head * 24];
#pragma unroll
        for (int j = 0; j < 3; j++) ((uint4*)dA)[j] = ((uint4*)tm)[j];
    }
    __syncthreads();

    // flush 160 rows x 96 f16 to osum[smap(r,l)]
    uint4* dst = (uint4*)osum;
    for (int i = t; i < 1920; i += 640) {
        int row = i / 12, seg = i % 12;
        int s2 = smap(r0 + row / 40, row % 40);
        size_t di = ((size_t)(b * 64000 + s2)) * 12 + seg;
        uint4 v = *(const uint4*)&kk[row * 104 + seg * 8];
        if (ACC) {
            half8 a = __builtin_bit_cast(half8, dst[di]);
            half8 c = __builtin_bit_cast(half8, v);
            dst[di] = __builtin_bit_cast(uint4, a + c);
        } else {
            dst[di] = v;
        }
    }
}

// ---------------- proj GEMM: out[b][c][s] = proj_w @ osum[b][s][96] + pb ----------------
__global__ __launch_bounds__(256) void k_proj(const _Float16* __restrict__ osum,
                                              const _Float16* __restrict__ wp,  // [96][96]
                                              const float* __restrict__ pb,
                                              float* __restrict__ out) {
    __shared__ _Float16 A[9216];
    __shared__ float bias_s[96];
    int t = threadIdx.x;
    int bid = blockIdx.x;
    int b = bid / 500;
    int s0 = (bid % 500) * 128;
    for (int i = t; i < 1152; i += 256) ((uint4*)A)[i] = ((const uint4*)wp)[i];
    if (t < 96) bias_s[t] = pb[t];
    __syncthreads();

    int ws = t >> 6, lane = t & 63;
    int n = lane & 31, kg = lane >> 5;
    int s = s0 + ws * 32 + n;

    const uint4* brow = (const uint4*)(osum + ((size_t)(b * 64000 + s0 + ws * 32 + n)) * 96);
    uint4 bf[6];
#pragma unroll
    for (int kc = 0; kc < 6; kc++) bf[kc] = brow[kc * 2 + kg];

    floatx16 acc[3];
#pragma unroll
    for (int mt = 0; mt < 3; mt++)
#pragma unroll
        for (int r = 0; r < 16; r++) acc[mt][r] = 0.f;

#pragma unroll
    for (int kc = 0; kc < 6; kc++) {
        half8 bfh = __builtin_bit_cast(half8, bf[kc]);
#pragma unroll
        for (int mt = 0; mt < 3; mt++) {
            uint4 au = *(const uint4*)&A[(mt * 32 + n) * 96 + kc * 16 + kg * 8];
            acc[mt] = __builtin_amdgcn_mfma_f32_32x32x16_f16(__builtin_bit_cast(half8, au), bfh, acc[mt], 0, 0, 0);
        }
    }

#pragma unroll
    for (int mt = 0; mt < 3; mt++)
#pragma unroll
        for (int r = 0; r < 16; r++) {
            int m = mt * 32 + (r & 3) + 8 * (r >> 2) + 4 * kg;
            out[((size_t)(b * 96 + m)) * 64000 + s] = acc[mt][r] + bias_s[m];
        }
}

extern "C" void kernel_launch(void* const* d_in, const int* in_sizes, int n_in,
                              void* d_out, int out_size, void* d_ws, size_t ws_size,
                              hipStream_t stream) {
    const float* x      = (const float*)d_in[0];
    const float* pos    = (const float*)d_in[1];
    const float* qkv_w  = (const float*)d_in[2];
    const float* qkv_b  = (const float*)d_in[3];
    const float* lp1_w  = (const float*)d_in[4];
    const float* lp1_b  = (const float*)d_in[5];
    const float* lp2_w  = (const float*)d_in[6];
    const float* lp2_b  = (const float*)d_in[7];
    const float* mod1_w = (const float*)d_in[8];
    const float* mod1_b = (const float*)d_in[9];
    const float* mod2_w = (const float*)d_in[10];
    const float* mod2_b = (const float*)d_in[11];
    // d_in[12..16]: pa_w, pa_b, R6_d, R6_h, R6_w — provably no-ops (see header)
    const float* proj_w = (const float*)d_in[17];
    const float* proj_b = (const float*)d_in[18];
    float* out = (float*)d_out;
    float* ws = (float*)d_ws;

    // f16 buffers (sizes in f32-float units of ws):
    _Float16* bufA = (_Float16*)ws;                        // 12.288M f16: c3/B0 -> xm
    _Float16* bufB = (_Float16*)(ws + 6144000);            // 12.288M f16: C2/D -> osum
    _Float16* qA   = (_Float16*)(ws + 12288000);           // 36.864M f16
    _Float16* in_t = qA;                                   // pos f16 [s][c], dead before qkv
    _Float16* wf   = (_Float16*)(ws + 30720000);           // 248,832 f16
    _Float16* wq   = (_Float16*)(ws + 30844416);           // 27,648 f16
    _Float16* wpj  = (_Float16*)(ws + 30858240);           // 9,216 f16
    _Float16* wfold= (_Float16*)(ws + 30862848);           // 9,216 f16
    _Float16* wm2  = (_Float16*)(ws + 30867456);           // 9,216 f16
    float* bfold   = ws + 30872064;                        // 96 f32
    float* raw     = ws + 30872160;                        // 768 f32 (raw0 | raw1)
    float* raw0 = raw, *raw1 = raw + 384;

    k_cvt_in<<<2016, 256, 0, stream>>>(pos, in_t);
    k_cvt_w<<<972, 256, 0, stream>>>(lp1_w, wf, raw);     // block 0 zeroes raw
    k_fold<<<36, 256, 0, stream>>>(lp2_w, lp2_b, mod1_w, mod1_b, wfold, bfold);
    k_cvt_f16<<<36, 256, 0, stream>>>(mod2_w, wm2, 9216);
    k_cvt_f16<<<108, 256, 0, stream>>>(qkv_w, wq, 27648);
    k_cvt_f16<<<36, 256, 0, stream>>>(proj_w, wpj, 9216);

    // c3 = conv3(pos)  [f16, [b][s][96]]
    k_conv3_v8<<<500, 256, 0, stream>>>(in_t, wf, lp1_b, bufA);
    // B0 = gelu(IN(c3)) in-place (finalize fused into ng16)
    k_stats_sc<<<500, 192, 0, stream>>>(bufA, raw0);
    k_ng16<<<1500, 256, 0, stream>>>(bufA, raw0);
    // C2 = W' @ B0 + b'   (folded lp2 -> mod1)
    k_gemm96<0><<<1000, 256, 0, stream>>>(bufA, wfold, bfold, nullptr, bufB);
    // D = gelu(IN(C2)) in-place
    k_stats_sc<<<500, 192, 0, stream>>>(bufB, raw1);
    k_ng16<<<1500, 256, 0, stream>>>(bufB, raw1);
    // xm = x * sigmoid(mod2 @ D + b)   [f16 [b][s][96], into bufA (B0 dead)]
    k_gemm96<1><<<1000, 256, 0, stream>>>(bufB, wm2, mod2_b, x, bufA);

    // qkv ONCE (s-order); qA overwrites in_t (dead)
    k_qkv<<<1000, 256, 0, stream>>>(bufA, wq, qkv_b, qA);
    // attention: axis 2 writes osum (contiguous), axes 0/1 accumulate
    k_attn<2, false><<<800, 640, 0, stream>>>(qA, bufB);
    k_attn<0, true ><<<800, 640, 0, stream>>>(qA, bufB);
    k_attn<1, true ><<<800, 640, 0, stream>>>(qA, bufB);

    // out = proj(osum)
    k_proj<<<1000, 256, 0, stream>>>(bufB, wpj, proj_b, out);
}

// Round 13
// 673.484 us; speedup vs baseline: 1.0110x; 1.0022x over previous
//
#include <hip/hip_runtime.h>

// Problem constants: B=2, C=96, D=H=W=40, S=64000, NH=4, HD=24, L=40
// Exact simplifications vs reference:
//  - pos_attn branch dropped (softmax row-shift invariance)
//  - R6 rotations dropped (R orthogonal; (Rq).(Rk) = q.k; v unrotated)
//  - mod1@ (lp2@B + b2) + b1 folded to W'@B + b'  (W' = mod1@lp2, exact)
// conv3 history: r7 XCD swizzle; r13 A via global_load_lds dbuf (98us);
// r16(v8b) compact tables -> 90us; v9 8-wave regressed (122us): conv3 FROZEN.
// r18: attn 4-line blocks but __launch_bounds__(640) WITHOUT min-waves ->
// compiler capped VGPR at 44 -> s[40]/pw/o spilled to scratch: WRITE 131MB,
// 93us/dispatch (spill-BW-bound). Counters finally show attn as the dominant
// rest cost (~90us each even in r16).
// r19: single fix: __launch_bounds__(640, 3) -> VGPR cap ~170 (needs ~120,
// no spill), 10 waves fit 3/3/2/2 per SIMD. Tests the 768B-quad gather
// theory unconfounded. stats-500 kept; all else unchanged.

typedef __attribute__((ext_vector_type(8))) _Float16 half8;
typedef __attribute__((ext_vector_type(2))) _Float16 half2;
typedef __attribute__((ext_vector_type(16))) float floatx16;

static __device__ __forceinline__ half2 h2(unsigned int u) {
    return __builtin_bit_cast(half2, u);
}
static __device__ __forceinline__ float fdot2(unsigned int a, unsigned int b, float c) {
    return __builtin_amdgcn_fdot2(h2(a), h2(b), c, false);
}

typedef __attribute__((address_space(1))) const void gas_t;
typedef __attribute__((address_space(3))) void las_t;
static __device__ __forceinline__ void gll16(const void* g, void* l) {
    __builtin_amdgcn_global_load_lds((gas_t*)g, (las_t*)l, 16, 0, 0);
}

// ---------------- prep: pos fp32 [b][c][s] -> f16 [b][s][c], XCD-aligned ----------------
__global__ __launch_bounds__(256) void k_cvt_in(const float* __restrict__ pos,
                                                _Float16* __restrict__ in_t) {
    __shared__ _Float16 lds[64][97];
    int bid = blockIdx.x;
    int xcd = bid & 7, k = bid >> 3;      // k 0..251
    int L;
    if (xcd < 4) L = xcd * 63 + (k >> 2);
    else { if (k >= 248) return; L = 252 + (xcd - 4) * 62 + (k >> 2); }
    int q = k & 3;
    int b = L / 250;
    int s0 = (L % 250) * 256 + q * 64;
    int t = threadIdx.x;
    for (int i = t; i < 6144; i += 256) {
        int c = i / 64, sl = i % 64;
        lds[sl][c] = (_Float16)pos[(b * 96 + c) * 64000 + s0 + sl];
    }
    __syncthreads();
    _Float16* outp = in_t + ((size_t)b * 64000 + s0) * 96;
    for (int i = t; i < 6144; i += 256) {
        int sl = i / 96, c = i % 96;
        outp[i] = lds[sl][c];
    }
}

// ---------------- prep: lp1_w [o][c][tap] -> f16 wf [tap][o][c]; block 0 zeroes raw ----------------
__global__ void k_cvt_w(const float* __restrict__ w, _Float16* __restrict__ wf,
                        float* __restrict__ raw) {
    int i = blockIdx.x * 256 + threadIdx.x;
    if (i < 248832) {
        int c = i % 96, m = (i / 96) % 96, tap = i / 9216;
        wf[i] = (_Float16)w[(m * 96 + c) * 27 + tap];
    }
    if (blockIdx.x == 0) {
        for (int u = threadIdx.x; u < 768; u += 256) raw[u] = 0.f;
    }
}

// ---------------- prep: f32 -> f16 straight copy ----------------
__global__ void k_cvt_f16(const float* __restrict__ w, _Float16* __restrict__ o, int n) {
    int i = blockIdx.x * 256 + threadIdx.x;
    if (i < n) o[i] = (_Float16)w[i];
}

// ---------------- prep: W' = mod1_w @ lp2_w (f16), b' = mod1_w @ lp2_b + mod1_b ----------------
__global__ __launch_bounds__(256) void k_fold(const float* __restrict__ lp2_w,
                                              const float* __restrict__ lp2_b,
                                              const float* __restrict__ mod1_w,
                                              const float* __restrict__ mod1_b,
                                              _Float16* __restrict__ wfold,
                                              float* __restrict__ bfold) {
    int i = blockIdx.x * 256 + threadIdx.x;   // grid 36 -> 9216 outputs
    if (i < 9216) {
        int o = i / 96, c = i % 96;
        float a = 0.f;
        for (int k = 0; k < 96; k++) a += mod1_w[o * 96 + k] * lp2_w[k * 96 + c];
        wfold[i] = (_Float16)a;
    }
    if (blockIdx.x == 0 && threadIdx.x < 96) {
        int o = threadIdx.x;
        float a = mod1_b[o];
        for (int k = 0; k < 96; k++) a += mod1_w[o * 96 + k] * lp2_b[k];
        bfold[o] = a;
    }
}

// ---------------- conv 3x3x3 circular: v8b (frozen best: 90us) ----------------
__global__ __launch_bounds__(256) void k_conv3_v8(const _Float16* __restrict__ in_t,
                                                  const _Float16* __restrict__ wf,  // [tap][m][c]
                                                  const float* __restrict__ bias,
                                                  _Float16* __restrict__ c3) {
    // smem: adh int[9][256] @0 (9216) | A dbuf 2x18432 @9216 (ends 46080)
    //       | bsh float[96] @50176 (384, OUTSIDE st range). st f16[256*98] @0.
    __shared__ __align__(16) char smem[50560];
    int* adh = (int*)smem;
    char* Ab = smem + 9216;
    float* bsh = (float*)(smem + 50176);
    _Float16* st = (_Float16*)smem;

    int t = threadIdx.x;
    int bid = blockIdx.x;
    {   // bijective XCD-chunked remap (nwg=500: q=62, r=4)
        int xcd = bid & 7, idx = bid >> 3;
        bid = (xcd < 4) ? (xcd * 63 + idx) : (252 + (xcd - 4) * 62 + idx);
    }
    int b = bid / 250;
    int s0 = (bid % 250) * 256;

    int wv = t >> 6, lane = t & 63;
    int n31 = lane & 31, kg = lane >> 5;

    int goff[5];
#pragma unroll
    for (int i = 0; i < 5; i++) {
        int k = wv + 4 * i;
        if (k < 18) {
            int u = k * 64 + lane;
            int row = u % 96, blk = u / 96;
            goff[i] = row * 192 + (blk >> 1) * 32 + (blk & 1) * 16;
        }
    }
    {
        const char* src = (const char*)wf;
#pragma unroll
        for (int i = 0; i < 5; i++) {
            int k = wv + 4 * i;
            if (k < 18) gll16(src + goff[i], Ab + k * 1024);
        }
    }

    {
        int s = s0 + t;
        int d = s / 1600, rr = s - d * 1600;
        int h = rr / 40;
#pragma unroll
        for (int kd = 0; kd < 3; kd++) {
            int dd = d + kd - 1; if (dd < 0) dd += 40; else if (dd >= 40) dd -= 40;
#pragma unroll
            for (int kh = 0; kh < 3; kh++) {
                int hh = h + kh - 1; if (hh < 0) hh += 40; else if (hh >= 40) hh -= 40;
                adh[(kd * 3 + kh) * 256 + t] = dd * 307200 + hh * 7680;
            }
        }
    }
    if (t < 96) bsh[t] = bias[t];

    int r0s = s0 + wv * 64 + n31;
    int w0 = r0s % 40;
    int w1 = (r0s + 32) % 40;
    __syncthreads();   // adh ready AND tap-0 A landed

    const char* inb = (const char*)(in_t + (size_t)b * 64000 * 96) + kg * 16;

    floatx16 acc[3][2];
#pragma unroll
    for (int mt = 0; mt < 3; mt++)
#pragma unroll
        for (int nt = 0; nt < 2; nt++)
#pragma unroll
            for (int r = 0; r < 16; r++) acc[mt][nt][r] = 0.f;

    for (int tap = 0; tap < 27; tap++) {
        int cur = tap & 1;
        if (tap < 26) {
            const char* src = (const char*)wf + (tap + 1) * 18432;
            char* dstb = Ab + (cur ^ 1) * 18432;
#pragma unroll
            for (int i = 0; i < 5; i++) {
                int k = wv + 4 * i;
                if (k < 18) gll16(src + goff[i], dstb + k * 1024);
            }
        }
        int kdh = tap / 3, kw = tap - kdh * 3;
        int a0 = adh[kdh * 256 + wv * 64 + n31];
        int a1 = adh[kdh * 256 + wv * 64 + 32 + n31];
        int ww0 = w0 + kw - 1; if (ww0 < 0) ww0 += 40; else if (ww0 >= 40) ww0 -= 40;
        int ww1 = w1 + kw - 1; if (ww1 < 0) ww1 += 40; else if (ww1 >= 40) ww1 -= 40;
        const char* pb0 = inb + a0 + ww0 * 192;
        const char* pb1 = inb + a1 + ww1 * 192;
        const char* Ac = Ab + cur * 18432 + kg * 1536 + n31 * 16;
#pragma unroll
        for (int j = 0; j < 6; j++) {
            half8 b0 = *(const half8*)(pb0 + j * 32);
            half8 b1 = *(const half8*)(pb1 + j * 32);
            const char* Aj = Ac + j * 3072;
            half8 a0f = *(const half8*)(Aj);
            half8 a1f = *(const half8*)(Aj + 512);
            half8 a2f = *(const half8*)(Aj + 1024);
            acc[0][0] = __builtin_amdgcn_mfma_f32_32x32x16_f16(a0f, b0, acc[0][0], 0, 0, 0);
            acc[0][1] = __builtin_amdgcn_mfma_f32_32x32x16_f16(a0f, b1, acc[0][1], 0, 0, 0);
            acc[1][0] = __builtin_amdgcn_mfma_f32_32x32x16_f16(a1f, b0, acc[1][0], 0, 0, 0);
            acc[1][1] = __builtin_amdgcn_mfma_f32_32x32x16_f16(a1f, b1, acc[1][1], 0, 0, 0);
            acc[2][0] = __builtin_amdgcn_mfma_f32_32x32x16_f16(a2f, b0, acc[2][0], 0, 0, 0);
            acc[2][1] = __builtin_amdgcn_mfma_f32_32x32x16_f16(a2f, b1, acc[2][1], 0, 0, 0);
        }
        __syncthreads();
    }

#pragma unroll
    for (int mt = 0; mt < 3; mt++)
#pragma unroll
        for (int nt = 0; nt < 2; nt++)
#pragma unroll
            for (int r = 0; r < 16; r++) {
                int m = mt * 32 + (r & 3) + 8 * (r >> 2) + 4 * kg;
                int sl = wv * 64 + nt * 32 + n31;
                st[sl * 98 + m] = (_Float16)(acc[mt][nt][r] + bsh[m]);
            }
    __syncthreads();

    unsigned int* dst = (unsigned int*)(c3 + ((size_t)(b * 64000 + s0)) * 96);
    for (int i = t; i < 12288; i += 256) {
        int row = i / 48, sg = i % 48;
        dst[i] = *(const unsigned int*)&st[row * 98 + sg * 2];
    }
}

// ---------------- per-(b,c) stats over f16 [b][s][96]: atomic partial sums ----------------
// grid 500 (256-s chunks) — full-GPU reduction.
__global__ __launch_bounds__(192) void k_stats_sc(const _Float16* __restrict__ in,
                                                  float* __restrict__ raw) {   // [192][2]
    __shared__ float red_s[16][96], red_q[16][96];
    int bid = blockIdx.x;            // 500 blocks: b = bid/250, chunk of 256 s
    int b = bid / 250, ch = bid % 250;
    int t = threadIdx.x;
    int sp = t / 12, cs = t % 12;
    const uint4* base = (const uint4*)(in + ((size_t)(b * 64000 + ch * 256)) * 96);
    float s8[8], q8[8];
#pragma unroll
    for (int e = 0; e < 8; e++) { s8[e] = 0.f; q8[e] = 0.f; }
#pragma unroll
    for (int i = 0; i < 16; i++) {
        uint4 v = base[(sp + i * 16) * 12 + cs];
        half8 h = __builtin_bit_cast(half8, v);
#pragma unroll
        for (int e = 0; e < 8; e++) { float f = (float)h[e]; s8[e] += f; q8[e] += f * f; }
    }
#pragma unroll
    for (int e = 0; e < 8; e++) { red_s[sp][cs * 8 + e] = s8[e]; red_q[sp][cs * 8 + e] = q8[e]; }
    __syncthreads();
    if (t < 96) {
        float S = 0.f, Q = 0.f;
        for (int k = 0; k < 16; k++) { S += red_s[k][t]; Q += red_q[k][t]; }
        atomicAdd(&raw[(b * 96 + t) * 2], S);
        atomicAdd(&raw[(b * 96 + t) * 2 + 1], Q);
    }
}

// ---------------- norm + exact gelu on f16 [b][s][96], in-place; finalize fused ----------------
__global__ __launch_bounds__(256) void k_ng16(_Float16* __restrict__ x, const float* __restrict__ raw) {
    __shared__ float2 sfs[192];
    int t = threadIdx.x, bid = blockIdx.x;
    if (t < 192) {
        float S = raw[t * 2], Q = raw[t * 2 + 1];
        float mu = S * (1.f / 64000.f);
        float var = Q * (1.f / 64000.f) - mu * mu;
        sfs[t] = make_float2(mu, rsqrtf(var + 1e-5f));
    }
    __syncthreads();
    uint4* p = (uint4*)x;
#pragma unroll
    for (int k = 0; k < 4; k++) {
        int i = bid * 1024 + k * 256 + t;      // uint4 index, 1,536,000 total
        int e0 = i * 8;
        int b = e0 / 6144000;
        int c0 = e0 % 96;
        const float2* sp = &sfs[b * 96 + c0];
        uint4 v = p[i];
        half8 h = __builtin_bit_cast(half8, v);
        _Float16 o[8];
#pragma unroll
        for (int e = 0; e < 8; e++) {
            float2 st = sp[e];
            float u = ((float)h[e] - st.x) * st.y;
            o[e] = (_Float16)(0.5f * u * (1.f + erff(u * 0.70710678118654752f)));
        }
        p[i] = *(uint4*)o;
    }
}

// ---------------- 96x96 f16 MFMA GEMM on [b][s][96]; MODE 1: sigmoid * x epilogue ----------------
template <int MODE>
__global__ __launch_bounds__(256) void k_gemm96(const _Float16* __restrict__ in,
                                                const _Float16* __restrict__ w,   // [96][96]
                                                const float* __restrict__ bias,
                                                const float* __restrict__ xg,     // [b][c][s] f32 (MODE 1)
                                                _Float16* __restrict__ outp) {
    __shared__ _Float16 un[12544];   // union: W (9216) | out staging 128 x 98
    __shared__ float bias_s[96];
    int t = threadIdx.x, bid = blockIdx.x;
    { int xcd = bid & 7; bid = xcd * 125 + (bid >> 3); }   // chain conv3's XCD map
    int b = bid / 500, s0 = (bid % 500) * 128;
    for (int i = t; i < 1152; i += 256) ((uint4*)un)[i] = ((const uint4*)w)[i];
    if (t < 96) bias_s[t] = bias[t];
    __syncthreads();

    int ws = t >> 6, lane = t & 63;
    int n = lane & 31, kg = lane >> 5;
    int p = ws * 32 + n;
    const uint4* brow = (const uint4*)(in + ((size_t)(b * 64000 + s0 + p)) * 96);
    uint4 bf[6];
#pragma unroll
    for (int kc = 0; kc < 6; kc++) bf[kc] = brow[kc * 2 + kg];

    floatx16 acc[3];
#pragma unroll
    for (int mt = 0; mt < 3; mt++)
#pragma unroll
        for (int r = 0; r < 16; r++) acc[mt][r] = 0.f;
#pragma unroll
    for (int kc = 0; kc < 6; kc++) {
        half8 bfh = __builtin_bit_cast(half8, bf[kc]);
#pragma unroll
        for (int mt = 0; mt < 3; mt++) {
            uint4 au = *(const uint4*)&un[(mt * 32 + n) * 96 + kc * 16 + kg * 8];
            acc[mt] = __builtin_amdgcn_mfma_f32_32x32x16_f16(__builtin_bit_cast(half8, au), bfh, acc[mt], 0, 0, 0);
        }
    }
    __syncthreads();   // done reading W; un becomes output staging

#pragma unroll
    for (int mt = 0; mt < 3; mt++)
#pragma unroll
        for (int r = 0; r < 16; r++) {
            int m = mt * 32 + (r & 3) + 8 * (r >> 2) + 4 * kg;
            int sl = ws * 32 + n;
            float v = acc[mt][r] + bias_s[m];
            if (MODE == 1) {
                v = 1.f / (1.f + __expf(-v));
                v *= xg[((size_t)(b * 96 + m)) * 64000 + s0 + sl];
            }
            un[sl * 98 + m] = (_Float16)v;
        }
    __syncthreads();

    unsigned int* dst = (unsigned int*)(outp + ((size_t)(b * 64000 + s0)) * 96);
    for (int i = t; i < 6144; i += 256) {
        int row = i / 48, sg = i % 48;
        dst[i] = *(const unsigned int*)&un[row * 98 + sg * 2];
    }
}

// ---------------- qkv GEMM (ONCE): qA[b][s][288] f16, natural s-order ----------------
__global__ __launch_bounds__(256) void k_qkv(const _Float16* __restrict__ xt,
                                             const _Float16* __restrict__ wq,  // [288][96]
                                             const float* __restrict__ qb,
                                             _Float16* __restrict__ qA) {
    __shared__ _Float16 smem[27648];   // union: A (288x96) then epi (64 x 296)
    __shared__ float bias_s[288];
    int t = threadIdx.x;
    int bid = blockIdx.x;
    { int xcd = bid & 7; bid = xcd * 125 + (bid >> 3); }   // chain conv3's XCD map
    int b = bid / 500;
    int s0 = (bid % 500) * 128;

    for (int i = t; i < 3456; i += 256) ((uint4*)smem)[i] = ((const uint4*)wq)[i];
    for (int i = t; i < 288; i += 256) bias_s[i] = qb[i];
    __syncthreads();

    int ws = t >> 6, lane = t & 63;
    int n = lane & 31, kg = lane >> 5;
    int p = ws * 32 + n;

    const uint4* brow = (const uint4*)(xt + ((size_t)(b * 64000 + s0 + p)) * 96);
    uint4 bf[6];
#pragma unroll
    for (int kc = 0; kc < 6; kc++) bf[kc] = brow[kc * 2 + kg];

    floatx16 acc[9];
#pragma unroll
    for (int mt = 0; mt < 9; mt++)
#pragma unroll
        for (int r = 0; r < 16; r++) acc[mt][r] = 0.f;

#pragma unroll
    for (int kc = 0; kc < 6; kc++) {
        half8 bfh = __builtin_bit_cast(half8, bf[kc]);
#pragma unroll
        for (int mt = 0; mt < 9; mt++) {
            uint4 au = *(const uint4*)&smem[(mt * 32 + n) * 96 + kc * 16 + kg * 8];
            acc[mt] = __builtin_amdgcn_mfma_f32_32x32x16_f16(__builtin_bit_cast(half8, au), bfh, acc[mt], 0, 0, 0);
        }
    }

    const float scale = 0.20412414523193154f;
    for (int q = 0; q < 2; q++) {
        __syncthreads();
        if ((ws >> 1) == q) {
            int pl = (ws & 1) * 32 + n;
#pragma unroll
            for (int mt = 0; mt < 9; mt++)
#pragma unroll
                for (int g = 0; g < 4; g++) {
                    int m0 = mt * 32 + g * 8 + kg * 4;
                    _Float16 tm[4];
#pragma unroll
                    for (int j = 0; j < 4; j++) {
                        float v = acc[mt][g * 4 + j] + bias_s[m0 + j];
                        if (m0 + j < 96) v *= scale;
                        tm[j] = (_Float16)v;
                    }
                    *(uint2*)&smem[pl * 296 + m0] = *(uint2*)tm;
                }
        }
        __syncthreads();
        for (int idx = t; idx < 2304; idx += 256) {
            int pl = idx / 36, seg = idx % 36;
            int s = s0 + q * 64 + pl;
            uint4 v = *(const uint4*)&smem[pl * 296 + seg * 8];
            *(uint4*)&qA[((size_t)(b * 64000 + s)) * 288 + seg * 8] = v;
        }
    }
}

// ---------------- fused axial attention: softmax + PV, sum into osum[b][s][96] ----------------
// 4 lines/block (640 thr, grid 800); (640,3): VGPR cap ~170 (needs ~120) -> NO SPILL.
template <int AXIS, bool ACC>
__global__ __launch_bounds__(640, 3) void k_attn(const _Float16* __restrict__ qA,
                                                 _Float16* __restrict__ osum) {
    __shared__ _Float16 kk[16640];    // k: [line][key][96] (15360); out staging [line][l][104] (16640)
    __shared__ _Float16 vT[15488];    // plane lh=line*4+head, stride 968: [hd][40 keys]
    int t = threadIdx.x;
    int bid = blockIdx.x;
    bid = (bid & 7) * 100 + (bid >> 3);   // bijective XCD chunking (800%8==0)
    int b = bid / 400;
    int r0 = (bid % 400) * 4;

    auto smap = [&](int r, int l) -> int {
        if (AXIS == 0) return l * 1600 + r;
        else if (AXIS == 1) { int d = r / 40, w = r % 40; return d * 1600 + l * 40 + w; }
        else return r * 40 + l;
    };
    const uint4* src = (const uint4*)qA;
    for (int i = t; i < 1920; i += 640) {
        int line = i / 480, key = (i % 480) / 12, seg = i % 12;
        int row = b * 64000 + smap(r0 + line, key);
        ((uint4*)kk)[i] = src[(size_t)row * 36 + 12 + seg];
    }
    for (int i = t; i < 1920; i += 640) {
        int line = i / 480, key = (i % 480) / 12, seg = i % 12;
        int row = b * 64000 + smap(r0 + line, key);
        uint4 v = src[(size_t)row * 36 + 24 + seg];
        _Float16 tmp[8];
        *(uint4*)tmp = v;
#pragma unroll
        for (int e = 0; e < 8; e++) {
            int hdg = seg * 8 + e;
            vT[(line * 4 + hdg / 24) * 968 + (hdg % 24) * 40 + key] = tmp[e];
        }
    }

    int line = t / 160, head = (t % 160) / 40, ql = t % 40;
    int rr = r0 + line;
    unsigned int qu[12];
    {
        const uint4* qp = (const uint4*)(qA + ((size_t)(b * 64000 + smap(rr, ql))) * 288 + head * 24);
#pragma unroll
        for (int j = 0; j < 3; j++) *(uint4*)&qu[j * 4] = qp[j];
    }
    __syncthreads();

    float s[40];
    const uint4* kbase = (const uint4*)kk + line * 480 + head * 3;
#pragma unroll 4
    for (int key = 0; key < 40; key++) {
        unsigned int kku[12];
#pragma unroll
        for (int j = 0; j < 3; j++) *(uint4*)&kku[j * 4] = kbase[key * 12 + j];
        float a = 0.f;
#pragma unroll
        for (int i = 0; i < 12; i++) a = fdot2(kku[i], qu[i], a);
        s[key] = a;
    }

    float mx = -1e30f;
#pragma unroll
    for (int i = 0; i < 40; i++) mx = fmaxf(mx, s[i]);
    float sum = 0.f;
#pragma unroll
    for (int i = 0; i < 40; i++) { s[i] = __expf(s[i] - mx); sum += s[i]; }
    float inv = 1.f / sum;

    unsigned int pw[20];
#pragma unroll
    for (int i = 0; i < 20; i++) {
        half2 a = { (_Float16)(s[2 * i] * inv), (_Float16)(s[2 * i + 1] * inv) };
        pw[i] = __builtin_bit_cast(unsigned int, a);
    }

    __syncthreads();   // kk becomes output staging

    float o[24];
    const uint4* vbase = (const uint4*)vT + (line * 4 + head) * 121;
#pragma unroll 2
    for (int hd = 0; hd < 24; hd++) {
        unsigned int vv[20];
#pragma unroll
        for (int j = 0; j < 5; j++) *(uint4*)&vv[j * 4] = vbase[hd * 5 + j];
        float a = 0.f;
#pragma unroll
        for (int i = 0; i < 20; i++) a = fdot2(vv[i], pw[i], a);
        o[hd] = a;
    }

    {
        _Float16 tm[24];
#pragma unroll
        for (int j = 0; j < 24; j++) tm[j] = (_Float16)o[j];
        _Float16* dA = &kk[(line * 40 + ql) * 104 + head * 24];
#pragma unroll
        for (int j = 0; j < 3; j++) ((uint4*)dA)[j] = ((uint4*)tm)[j];
    }
    __syncthreads();

    // flush 160 rows x 96 f16 to osum[smap(r,l)]
    uint4* dst = (uint4*)osum;
    for (int i = t; i < 1920; i += 640) {
        int row = i / 12, seg = i % 12;
        int s2 = smap(r0 + row / 40, row % 40);
        size_t di = ((size_t)(b * 64000 + s2)) * 12 + seg;
        uint4 v = *(const uint4*)&kk[row * 104 + seg * 8];
        if (ACC) {
            half8 a = __builtin_bit_cast(half8, dst[di]);
            half8 c = __builtin_bit_cast(half8, v);
            dst[di] = __builtin_bit_cast(uint4, a + c);
        } else {
            dst[di] = v;
        }
    }
}

// ---------------- proj GEMM: out[b][c][s] = proj_w @ osum[b][s][96] + pb ----------------
__global__ __launch_bounds__(256) void k_proj(const _Float16* __restrict__ osum,
                                              const _Float16* __restrict__ wp,  // [96][96]
                                              const float* __restrict__ pb,
                                              float* __restrict__ out) {
    __shared__ _Float16 A[9216];
    __shared__ float bias_s[96];
    int t = threadIdx.x;
    int bid = blockIdx.x;
    int b = bid / 500;
    int s0 = (bid % 500) * 128;
    for (int i = t; i < 1152; i += 256) ((uint4*)A)[i] = ((const uint4*)wp)[i];
    if (t < 96) bias_s[t] = pb[t];
    __syncthreads();

    int ws = t >> 6, lane = t & 63;
    int n = lane & 31, kg = lane >> 5;
    int s = s0 + ws * 32 + n;

    const uint4* brow = (const uint4*)(osum + ((size_t)(b * 64000 + s0 + ws * 32 + n)) * 96);
    uint4 bf[6];
#pragma unroll
    for (int kc = 0; kc < 6; kc++) bf[kc] = brow[kc * 2 + kg];

    floatx16 acc[3];
#pragma unroll
    for (int mt = 0; mt < 3; mt++)
#pragma unroll
        for (int r = 0; r < 16; r++) acc[mt][r] = 0.f;

#pragma unroll
    for (int kc = 0; kc < 6; kc++) {
        half8 bfh = __builtin_bit_cast(half8, bf[kc]);
#pragma unroll
        for (int mt = 0; mt < 3; mt++) {
            uint4 au = *(const uint4*)&A[(mt * 32 + n) * 96 + kc * 16 + kg * 8];
            acc[mt] = __builtin_amdgcn_mfma_f32_32x32x16_f16(__builtin_bit_cast(half8, au), bfh, acc[mt], 0, 0, 0);
        }
    }

#pragma unroll
    for (int mt = 0; mt < 3; mt++)
#pragma unroll
        for (int r = 0; r < 16; r++) {
            int m = mt * 32 + (r & 3) + 8 * (r >> 2) + 4 * kg;
            out[((size_t)(b * 96 + m)) * 64000 + s] = acc[mt][r] + bias_s[m];
        }
}

extern "C" void kernel_launch(void* const* d_in, const int* in_sizes, int n_in,
                              void* d_out, int out_size, void* d_ws, size_t ws_size,
                              hipStream_t stream) {
    const float* x      = (const float*)d_in[0];
    const float* pos    = (const float*)d_in[1];
    const float* qkv_w  = (const float*)d_in[2];
    const float* qkv_b  = (const float*)d_in[3];
    const float* lp1_w  = (const float*)d_in[4];
    const float* lp1_b  = (const float*)d_in[5];
    const float* lp2_w  = (const float*)d_in[6];
    const float* lp2_b  = (const float*)d_in[7];
    const float* mod1_w = (const float*)d_in[8];
    const float* mod1_b = (const float*)d_in[9];
    const float* mod2_w = (const float*)d_in[10];
    const float* mod2_b = (const float*)d_in[11];
    // d_in[12..16]: pa_w, pa_b, R6_d, R6_h, R6_w — provably no-ops (see header)
    const float* proj_w = (const float*)d_in[17];
    const float* proj_b = (const float*)d_in[18];
    float* out = (float*)d_out;
    float* ws = (float*)d_ws;

    // f16 buffers (sizes in f32-float units of ws):
    _Float16* bufA = (_Float16*)ws;                        // 12.288M f16: c3/B0 -> xm
    _Float16* bufB = (_Float16*)(ws + 6144000);            // 12.288M f16: C2/D -> osum
    _Float16* qA   = (_Float16*)(ws + 12288000);           // 36.864M f16
    _Float16* in_t = qA;                                   // pos f16 [s][c], dead before qkv
    _Float16* wf   = (_Float16*)(ws + 30720000);           // 248,832 f16
    _Float16* wq   = (_Float16*)(ws + 30844416);           // 27,648 f16
    _Float16* wpj  = (_Float16*)(ws + 30858240);           // 9,216 f16
    _Float16* wfold= (_Float16*)(ws + 30862848);           // 9,216 f16
    _Float16* wm2  = (_Float16*)(ws + 30867456);           // 9,216 f16
    float* bfold   = ws + 30872064;                        // 96 f32
    float* raw     = ws + 30872160;                        // 768 f32 (raw0 | raw1)
    float* raw0 = raw, *raw1 = raw + 384;

    k_cvt_in<<<2016, 256, 0, stream>>>(pos, in_t);
    k_cvt_w<<<972, 256, 0, stream>>>(lp1_w, wf, raw);     // block 0 zeroes raw
    k_fold<<<36, 256, 0, stream>>>(lp2_w, lp2_b, mod1_w, mod1_b, wfold, bfold);
    k_cvt_f16<<<36, 256, 0, stream>>>(mod2_w, wm2, 9216);
    k_cvt_f16<<<108, 256, 0, stream>>>(qkv_w, wq, 27648);
    k_cvt_f16<<<36, 256, 0, stream>>>(proj_w, wpj, 9216);

    // c3 = conv3(pos)  [f16, [b][s][96]]
    k_conv3_v8<<<500, 256, 0, stream>>>(in_t, wf, lp1_b, bufA);
    // B0 = gelu(IN(c3)) in-place (finalize fused into ng16)
    k_stats_sc<<<500, 192, 0, stream>>>(bufA, raw0);
    k_ng16<<<1500, 256, 0, stream>>>(bufA, raw0);
    // C2 = W' @ B0 + b'   (folded lp2 -> mod1)
    k_gemm96<0><<<1000, 256, 0, stream>>>(bufA, wfold, bfold, nullptr, bufB);
    // D = gelu(IN(C2)) in-place
    k_stats_sc<<<500, 192, 0, stream>>>(bufB, raw1);
    k_ng16<<<1500, 256, 0, stream>>>(bufB, raw1);
    // xm = x * sigmoid(mod2 @ D + b)   [f16 [b][s][96], into bufA (B0 dead)]
    k_gemm96<1><<<1000, 256, 0, stream>>>(bufB, wm2, mod2_b, x, bufA);

    // qkv ONCE (s-order); qA overwrites in_t (dead)
    k_qkv<<<1000, 256, 0, stream>>>(bufA, wq, qkv_b, qA);
    // attention: axis 2 writes osum (contiguous), axes 0/1 accumulate
    k_attn<2, false><<<800, 640, 0, stream>>>(qA, bufB);
    k_attn<0, true ><<<800, 640, 0, stream>>>(qA, bufB);
    k_attn<1, true ><<<800, 640, 0, stream>>>(qA, bufB);

    // out = proj(osum)
    k_proj<<<1000, 256, 0, stream>>>(bufB, wpj, proj_b, out);
}

// Round 14
// 602.948 us; speedup vs baseline: 1.1292x; 1.1170x over previous
//
#include <hip/hip_runtime.h>

// Problem constants: B=2, C=96, D=H=W=40, S=64000, NH=4, HD=24, L=40
// Exact simplifications vs reference:
//  - pos_attn branch dropped (softmax row-shift invariance)
//  - R6 rotations dropped (R orthogonal; (Rq).(Rk) = q.k; v unrotated)
//  - mod1@ (lp2@B + b2) + b1 folded to W'@B + b'  (W' = mod1@lp2, exact)
// conv3: FROZEN at v8b (90us). History in git.
// r18/r19: attn at 93-94us with VGPR_Count=44, WRITE 131MB — NOT a
// launch-bounds issue (r19's (640,3) changed nothing). ROOT CAUSE = rule #20:
// '#pragma unroll 4' / 'unroll 2' leave s[40]/o[24] runtime-indexed ->
// allocated in SCRATCH. attn has been scratch-BW-bound in every round.
// r20: FULL unroll of the 40-iter QK loop and 24-iter PV loop -> all array
// indices compile-time -> s/o in VGPRs (~100-160, fits (640,3) cap 170).
// 4-line shape kept (768B-quad gathers now unconfounded). All else unchanged.

typedef __attribute__((ext_vector_type(8))) _Float16 half8;
typedef __attribute__((ext_vector_type(2))) _Float16 half2;
typedef __attribute__((ext_vector_type(16))) float floatx16;

static __device__ __forceinline__ half2 h2(unsigned int u) {
    return __builtin_bit_cast(half2, u);
}
static __device__ __forceinline__ float fdot2(unsigned int a, unsigned int b, float c) {
    return __builtin_amdgcn_fdot2(h2(a), h2(b), c, false);
}

typedef __attribute__((address_space(1))) const void gas_t;
typedef __attribute__((address_space(3))) void las_t;
static __device__ __forceinline__ void gll16(const void* g, void* l) {
    __builtin_amdgcn_global_load_lds((gas_t*)g, (las_t*)l, 16, 0, 0);
}

// ---------------- prep: pos fp32 [b][c][s] -> f16 [b][s][c], XCD-aligned ----------------
__global__ __launch_bounds__(256) void k_cvt_in(const float* __restrict__ pos,
                                                _Float16* __restrict__ in_t) {
    __shared__ _Float16 lds[64][97];
    int bid = blockIdx.x;
    int xcd = bid & 7, k = bid >> 3;      // k 0..251
    int L;
    if (xcd < 4) L = xcd * 63 + (k >> 2);
    else { if (k >= 248) return; L = 252 + (xcd - 4) * 62 + (k >> 2); }
    int q = k & 3;
    int b = L / 250;
    int s0 = (L % 250) * 256 + q * 64;
    int t = threadIdx.x;
    for (int i = t; i < 6144; i += 256) {
        int c = i / 64, sl = i % 64;
        lds[sl][c] = (_Float16)pos[(b * 96 + c) * 64000 + s0 + sl];
    }
    __syncthreads();
    _Float16* outp = in_t + ((size_t)b * 64000 + s0) * 96;
    for (int i = t; i < 6144; i += 256) {
        int sl = i / 96, c = i % 96;
        outp[i] = lds[sl][c];
    }
}

// ---------------- prep: lp1_w [o][c][tap] -> f16 wf [tap][o][c]; block 0 zeroes raw ----------------
__global__ void k_cvt_w(const float* __restrict__ w, _Float16* __restrict__ wf,
                        float* __restrict__ raw) {
    int i = blockIdx.x * 256 + threadIdx.x;
    if (i < 248832) {
        int c = i % 96, m = (i / 96) % 96, tap = i / 9216;
        wf[i] = (_Float16)w[(m * 96 + c) * 27 + tap];
    }
    if (blockIdx.x == 0) {
        for (int u = threadIdx.x; u < 768; u += 256) raw[u] = 0.f;
    }
}

// ---------------- prep: f32 -> f16 straight copy ----------------
__global__ void k_cvt_f16(const float* __restrict__ w, _Float16* __restrict__ o, int n) {
    int i = blockIdx.x * 256 + threadIdx.x;
    if (i < n) o[i] = (_Float16)w[i];
}

// ---------------- prep: W' = mod1_w @ lp2_w (f16), b' = mod1_w @ lp2_b + mod1_b ----------------
__global__ __launch_bounds__(256) void k_fold(const float* __restrict__ lp2_w,
                                              const float* __restrict__ lp2_b,
                                              const float* __restrict__ mod1_w,
                                              const float* __restrict__ mod1_b,
                                              _Float16* __restrict__ wfold,
                                              float* __restrict__ bfold) {
    int i = blockIdx.x * 256 + threadIdx.x;   // grid 36 -> 9216 outputs
    if (i < 9216) {
        int o = i / 96, c = i % 96;
        float a = 0.f;
        for (int k = 0; k < 96; k++) a += mod1_w[o * 96 + k] * lp2_w[k * 96 + c];
        wfold[i] = (_Float16)a;
    }
    if (blockIdx.x == 0 && threadIdx.x < 96) {
        int o = threadIdx.x;
        float a = mod1_b[o];
        for (int k = 0; k < 96; k++) a += mod1_w[o * 96 + k] * lp2_b[k];
        bfold[o] = a;
    }
}

// ---------------- conv 3x3x3 circular: v8b (frozen best: 90us) ----------------
__global__ __launch_bounds__(256) void k_conv3_v8(const _Float16* __restrict__ in_t,
                                                  const _Float16* __restrict__ wf,  // [tap][m][c]
                                                  const float* __restrict__ bias,
                                                  _Float16* __restrict__ c3) {
    // smem: adh int[9][256] @0 (9216) | A dbuf 2x18432 @9216 (ends 46080)
    //       | bsh float[96] @50176 (384, OUTSIDE st range). st f16[256*98] @0.
    __shared__ __align__(16) char smem[50560];
    int* adh = (int*)smem;
    char* Ab = smem + 9216;
    float* bsh = (float*)(smem + 50176);
    _Float16* st = (_Float16*)smem;

    int t = threadIdx.x;
    int bid = blockIdx.x;
    {   // bijective XCD-chunked remap (nwg=500: q=62, r=4)
        int xcd = bid & 7, idx = bid >> 3;
        bid = (xcd < 4) ? (xcd * 63 + idx) : (252 + (xcd - 4) * 62 + idx);
    }
    int b = bid / 250;
    int s0 = (bid % 250) * 256;

    int wv = t >> 6, lane = t & 63;
    int n31 = lane & 31, kg = lane >> 5;

    int goff[5];
#pragma unroll
    for (int i = 0; i < 5; i++) {
        int k = wv + 4 * i;
        if (k < 18) {
            int u = k * 64 + lane;
            int row = u % 96, blk = u / 96;
            goff[i] = row * 192 + (blk >> 1) * 32 + (blk & 1) * 16;
        }
    }
    {
        const char* src = (const char*)wf;
#pragma unroll
        for (int i = 0; i < 5; i++) {
            int k = wv + 4 * i;
            if (k < 18) gll16(src + goff[i], Ab + k * 1024);
        }
    }

    {
        int s = s0 + t;
        int d = s / 1600, rr = s - d * 1600;
        int h = rr / 40;
#pragma unroll
        for (int kd = 0; kd < 3; kd++) {
            int dd = d + kd - 1; if (dd < 0) dd += 40; else if (dd >= 40) dd -= 40;
#pragma unroll
            for (int kh = 0; kh < 3; kh++) {
                int hh = h + kh - 1; if (hh < 0) hh += 40; else if (hh >= 40) hh -= 40;
                adh[(kd * 3 + kh) * 256 + t] = dd * 307200 + hh * 7680;
            }
        }
    }
    if (t < 96) bsh[t] = bias[t];

    int r0s = s0 + wv * 64 + n31;
    int w0 = r0s % 40;
    int w1 = (r0s + 32) % 40;
    __syncthreads();   // adh ready AND tap-0 A landed

    const char* inb = (const char*)(in_t + (size_t)b * 64000 * 96) + kg * 16;

    floatx16 acc[3][2];
#pragma unroll
    for (int mt = 0; mt < 3; mt++)
#pragma unroll
        for (int nt = 0; nt < 2; nt++)
#pragma unroll
            for (int r = 0; r < 16; r++) acc[mt][nt][r] = 0.f;

    for (int tap = 0; tap < 27; tap++) {
        int cur = tap & 1;
        if (tap < 26) {
            const char* src = (const char*)wf + (tap + 1) * 18432;
            char* dstb = Ab + (cur ^ 1) * 18432;
#pragma unroll
            for (int i = 0; i < 5; i++) {
                int k = wv + 4 * i;
                if (k < 18) gll16(src + goff[i], dstb + k * 1024);
            }
        }
        int kdh = tap / 3, kw = tap - kdh * 3;
        int a0 = adh[kdh * 256 + wv * 64 + n31];
        int a1 = adh[kdh * 256 + wv * 64 + 32 + n31];
        int ww0 = w0 + kw - 1; if (ww0 < 0) ww0 += 40; else if (ww0 >= 40) ww0 -= 40;
        int ww1 = w1 + kw - 1; if (ww1 < 0) ww1 += 40; else if (ww1 >= 40) ww1 -= 40;
        const char* pb0 = inb + a0 + ww0 * 192;
        const char* pb1 = inb + a1 + ww1 * 192;
        const char* Ac = Ab + cur * 18432 + kg * 1536 + n31 * 16;
#pragma unroll
        for (int j = 0; j < 6; j++) {
            half8 b0 = *(const half8*)(pb0 + j * 32);
            half8 b1 = *(const half8*)(pb1 + j * 32);
            const char* Aj = Ac + j * 3072;
            half8 a0f = *(const half8*)(Aj);
            half8 a1f = *(const half8*)(Aj + 512);
            half8 a2f = *(const half8*)(Aj + 1024);
            acc[0][0] = __builtin_amdgcn_mfma_f32_32x32x16_f16(a0f, b0, acc[0][0], 0, 0, 0);
            acc[0][1] = __builtin_amdgcn_mfma_f32_32x32x16_f16(a0f, b1, acc[0][1], 0, 0, 0);
            acc[1][0] = __builtin_amdgcn_mfma_f32_32x32x16_f16(a1f, b0, acc[1][0], 0, 0, 0);
            acc[1][1] = __builtin_amdgcn_mfma_f32_32x32x16_f16(a1f, b1, acc[1][1], 0, 0, 0);
            acc[2][0] = __builtin_amdgcn_mfma_f32_32x32x16_f16(a2f, b0, acc[2][0], 0, 0, 0);
            acc[2][1] = __builtin_amdgcn_mfma_f32_32x32x16_f16(a2f, b1, acc[2][1], 0, 0, 0);
        }
        __syncthreads();
    }

#pragma unroll
    for (int mt = 0; mt < 3; mt++)
#pragma unroll
        for (int nt = 0; nt < 2; nt++)
#pragma unroll
            for (int r = 0; r < 16; r++) {
                int m = mt * 32 + (r & 3) + 8 * (r >> 2) + 4 * kg;
                int sl = wv * 64 + nt * 32 + n31;
                st[sl * 98 + m] = (_Float16)(acc[mt][nt][r] + bsh[m]);
            }
    __syncthreads();

    unsigned int* dst = (unsigned int*)(c3 + ((size_t)(b * 64000 + s0)) * 96);
    for (int i = t; i < 12288; i += 256) {
        int row = i / 48, sg = i % 48;
        dst[i] = *(const unsigned int*)&st[row * 98 + sg * 2];
    }
}

// ---------------- per-(b,c) stats over f16 [b][s][96]: atomic partial sums ----------------
// grid 500 (256-s chunks) — full-GPU reduction.
__global__ __launch_bounds__(192) void k_stats_sc(const _Float16* __restrict__ in,
                                                  float* __restrict__ raw) {   // [192][2]
    __shared__ float red_s[16][96], red_q[16][96];
    int bid = blockIdx.x;            // 500 blocks: b = bid/250, chunk of 256 s
    int b = bid / 250, ch = bid % 250;
    int t = threadIdx.x;
    int sp = t / 12, cs = t % 12;
    const uint4* base = (const uint4*)(in + ((size_t)(b * 64000 + ch * 256)) * 96);
    float s8[8], q8[8];
#pragma unroll
    for (int e = 0; e < 8; e++) { s8[e] = 0.f; q8[e] = 0.f; }
#pragma unroll
    for (int i = 0; i < 16; i++) {
        uint4 v = base[(sp + i * 16) * 12 + cs];
        half8 h = __builtin_bit_cast(half8, v);
#pragma unroll
        for (int e = 0; e < 8; e++) { float f = (float)h[e]; s8[e] += f; q8[e] += f * f; }
    }
#pragma unroll
    for (int e = 0; e < 8; e++) { red_s[sp][cs * 8 + e] = s8[e]; red_q[sp][cs * 8 + e] = q8[e]; }
    __syncthreads();
    if (t < 96) {
        float S = 0.f, Q = 0.f;
        for (int k = 0; k < 16; k++) { S += red_s[k][t]; Q += red_q[k][t]; }
        atomicAdd(&raw[(b * 96 + t) * 2], S);
        atomicAdd(&raw[(b * 96 + t) * 2 + 1], Q);
    }
}

// ---------------- norm + exact gelu on f16 [b][s][96], in-place; finalize fused ----------------
__global__ __launch_bounds__(256) void k_ng16(_Float16* __restrict__ x, const float* __restrict__ raw) {
    __shared__ float2 sfs[192];
    int t = threadIdx.x, bid = blockIdx.x;
    if (t < 192) {
        float S = raw[t * 2], Q = raw[t * 2 + 1];
        float mu = S * (1.f / 64000.f);
        float var = Q * (1.f / 64000.f) - mu * mu;
        sfs[t] = make_float2(mu, rsqrtf(var + 1e-5f));
    }
    __syncthreads();
    uint4* p = (uint4*)x;
#pragma unroll
    for (int k = 0; k < 4; k++) {
        int i = bid * 1024 + k * 256 + t;      // uint4 index, 1,536,000 total
        int e0 = i * 8;
        int b = e0 / 6144000;
        int c0 = e0 % 96;
        const float2* sp = &sfs[b * 96 + c0];
        uint4 v = p[i];
        half8 h = __builtin_bit_cast(half8, v);
        _Float16 o[8];
#pragma unroll
        for (int e = 0; e < 8; e++) {
            float2 st = sp[e];
            float u = ((float)h[e] - st.x) * st.y;
            o[e] = (_Float16)(0.5f * u * (1.f + erff(u * 0.70710678118654752f)));
        }
        p[i] = *(uint4*)o;
    }
}

// ---------------- 96x96 f16 MFMA GEMM on [b][s][96]; MODE 1: sigmoid * x epilogue ----------------
template <int MODE>
__global__ __launch_bounds__(256) void k_gemm96(const _Float16* __restrict__ in,
                                                const _Float16* __restrict__ w,   // [96][96]
                                                const float* __restrict__ bias,
                                                const float* __restrict__ xg,     // [b][c][s] f32 (MODE 1)
                                                _Float16* __restrict__ outp) {
    __shared__ _Float16 un[12544];   // union: W (9216) | out staging 128 x 98
    __shared__ float bias_s[96];
    int t = threadIdx.x, bid = blockIdx.x;
    { int xcd = bid & 7; bid = xcd * 125 + (bid >> 3); }   // chain conv3's XCD map
    int b = bid / 500, s0 = (bid % 500) * 128;
    for (int i = t; i < 1152; i += 256) ((uint4*)un)[i] = ((const uint4*)w)[i];
    if (t < 96) bias_s[t] = bias[t];
    __syncthreads();

    int ws = t >> 6, lane = t & 63;
    int n = lane & 31, kg = lane >> 5;
    int p = ws * 32 + n;
    const uint4* brow = (const uint4*)(in + ((size_t)(b * 64000 + s0 + p)) * 96);
    uint4 bf[6];
#pragma unroll
    for (int kc = 0; kc < 6; kc++) bf[kc] = brow[kc * 2 + kg];

    floatx16 acc[3];
#pragma unroll
    for (int mt = 0; mt < 3; mt++)
#pragma unroll
        for (int r = 0; r < 16; r++) acc[mt][r] = 0.f;
#pragma unroll
    for (int kc = 0; kc < 6; kc++) {
        half8 bfh = __builtin_bit_cast(half8, bf[kc]);
#pragma unroll
        for (int mt = 0; mt < 3; mt++) {
            uint4 au = *(const uint4*)&un[(mt * 32 + n) * 96 + kc * 16 + kg * 8];
            acc[mt] = __builtin_amdgcn_mfma_f32_32x32x16_f16(__builtin_bit_cast(half8, au), bfh, acc[mt], 0, 0, 0);
        }
    }
    __syncthreads();   // done reading W; un becomes output staging

#pragma unroll
    for (int mt = 0; mt < 3; mt++)
#pragma unroll
        for (int r = 0; r < 16; r++) {
            int m = mt * 32 + (r & 3) + 8 * (r >> 2) + 4 * kg;
            int sl = ws * 32 + n;
            float v = acc[mt][r] + bias_s[m];
            if (MODE == 1) {
                v = 1.f / (1.f + __expf(-v));
                v *= xg[((size_t)(b * 96 + m)) * 64000 + s0 + sl];
            }
            un[sl * 98 + m] = (_Float16)v;
        }
    __syncthreads();

    unsigned int* dst = (unsigned int*)(outp + ((size_t)(b * 64000 + s0)) * 96);
    for (int i = t; i < 6144; i += 256) {
        int row = i / 48, sg = i % 48;
        dst[i] = *(const unsigned int*)&un[row * 98 + sg * 2];
    }
}

// ---------------- qkv GEMM (ONCE): qA[b][s][288] f16, natural s-order ----------------
__global__ __launch_bounds__(256) void k_qkv(const _Float16* __restrict__ xt,
                                             const _Float16* __restrict__ wq,  // [288][96]
                                             const float* __restrict__ qb,
                                             _Float16* __restrict__ qA) {
    __shared__ _Float16 smem[27648];   // union: A (288x96) then epi (64 x 296)
    __shared__ float bias_s[288];
    int t = threadIdx.x;
    int bid = blockIdx.x;
    { int xcd = bid & 7; bid = xcd * 125 + (bid >> 3); }   // chain conv3's XCD map
    int b = bid / 500;
    int s0 = (bid % 500) * 128;

    for (int i = t; i < 3456; i += 256) ((uint4*)smem)[i] = ((const uint4*)wq)[i];
    for (int i = t; i < 288; i += 256) bias_s[i] = qb[i];
    __syncthreads();

    int ws = t >> 6, lane = t & 63;
    int n = lane & 31, kg = lane >> 5;
    int p = ws * 32 + n;

    const uint4* brow = (const uint4*)(xt + ((size_t)(b * 64000 + s0 + p)) * 96);
    uint4 bf[6];
#pragma unroll
    for (int kc = 0; kc < 6; kc++) bf[kc] = brow[kc * 2 + kg];

    floatx16 acc[9];
#pragma unroll
    for (int mt = 0; mt < 9; mt++)
#pragma unroll
        for (int r = 0; r < 16; r++) acc[mt][r] = 0.f;

#pragma unroll
    for (int kc = 0; kc < 6; kc++) {
        half8 bfh = __builtin_bit_cast(half8, bf[kc]);
#pragma unroll
        for (int mt = 0; mt < 9; mt++) {
            uint4 au = *(const uint4*)&smem[(mt * 32 + n) * 96 + kc * 16 + kg * 8];
            acc[mt] = __builtin_amdgcn_mfma_f32_32x32x16_f16(__builtin_bit_cast(half8, au), bfh, acc[mt], 0, 0, 0);
        }
    }

    const float scale = 0.20412414523193154f;
    for (int q = 0; q < 2; q++) {
        __syncthreads();
        if ((ws >> 1) == q) {
            int pl = (ws & 1) * 32 + n;
#pragma unroll
            for (int mt = 0; mt < 9; mt++)
#pragma unroll
                for (int g = 0; g < 4; g++) {
                    int m0 = mt * 32 + g * 8 + kg * 4;
                    _Float16 tm[4];
#pragma unroll
                    for (int j = 0; j < 4; j++) {
                        float v = acc[mt][g * 4 + j] + bias_s[m0 + j];
                        if (m0 + j < 96) v *= scale;
                        tm[j] = (_Float16)v;
                    }
                    *(uint2*)&smem[pl * 296 + m0] = *(uint2*)tm;
                }
        }
        __syncthreads();
        for (int idx = t; idx < 2304; idx += 256) {
            int pl = idx / 36, seg = idx % 36;
            int s = s0 + q * 64 + pl;
            uint4 v = *(const uint4*)&smem[pl * 296 + seg * 8];
            *(uint4*)&qA[((size_t)(b * 64000 + s)) * 288 + seg * 8] = v;
        }
    }
}

// ---------------- fused axial attention: softmax + PV, sum into osum[b][s][96] ----------------
// 4 lines/block (640 thr, grid 800), (640,3). r20: FULL unroll of QK (40) and
// PV (24) loops -> s[]/o[] compile-time indexed -> registers, not scratch.
template <int AXIS, bool ACC>
__global__ __launch_bounds__(640, 3) void k_attn(const _Float16* __restrict__ qA,
                                                 _Float16* __restrict__ osum) {
    __shared__ _Float16 kk[16640];    // k: [line][key][96] (15360); out staging [line][l][104] (16640)
    __shared__ _Float16 vT[15488];    // plane lh=line*4+head, stride 968: [hd][40 keys]
    int t = threadIdx.x;
    int bid = blockIdx.x;
    bid = (bid & 7) * 100 + (bid >> 3);   // bijective XCD chunking (800%8==0)
    int b = bid / 400;
    int r0 = (bid % 400) * 4;

    auto smap = [&](int r, int l) -> int {
        if (AXIS == 0) return l * 1600 + r;
        else if (AXIS == 1) { int d = r / 40, w = r % 40; return d * 1600 + l * 40 + w; }
        else return r * 40 + l;
    };
    const uint4* src = (const uint4*)qA;
    for (int i = t; i < 1920; i += 640) {
        int line = i / 480, key = (i % 480) / 12, seg = i % 12;
        int row = b * 64000 + smap(r0 + line, key);
        ((uint4*)kk)[i] = src[(size_t)row * 36 + 12 + seg];
    }
    for (int i = t; i < 1920; i += 640) {
        int line = i / 480, key = (i % 480) / 12, seg = i % 12;
        int row = b * 64000 + smap(r0 + line, key);
        uint4 v = src[(size_t)row * 36 + 24 + seg];
        _Float16 tmp[8];
        *(uint4*)tmp = v;
#pragma unroll
        for (int e = 0; e < 8; e++) {
            int hdg = seg * 8 + e;
            vT[(line * 4 + hdg / 24) * 968 + (hdg % 24) * 40 + key] = tmp[e];
        }
    }

    int line = t / 160, head = (t % 160) / 40, ql = t % 40;
    int rr = r0 + line;
    unsigned int qu[12];
    {
        const uint4* qp = (const uint4*)(qA + ((size_t)(b * 64000 + smap(rr, ql))) * 288 + head * 24);
#pragma unroll
        for (int j = 0; j < 3; j++) *(uint4*)&qu[j * 4] = qp[j];
    }
    __syncthreads();

    float s[40];
    const uint4* kbase = (const uint4*)kk + line * 480 + head * 3;
#pragma unroll
    for (int key = 0; key < 40; key++) {
        unsigned int kku[12];
#pragma unroll
        for (int j = 0; j < 3; j++) *(uint4*)&kku[j * 4] = kbase[key * 12 + j];
        float a = 0.f;
#pragma unroll
        for (int i = 0; i < 12; i++) a = fdot2(kku[i], qu[i], a);
        s[key] = a;
    }

    float mx = -1e30f;
#pragma unroll
    for (int i = 0; i < 40; i++) mx = fmaxf(mx, s[i]);
    float sum = 0.f;
#pragma unroll
    for (int i = 0; i < 40; i++) { s[i] = __expf(s[i] - mx); sum += s[i]; }
    float inv = 1.f / sum;

    unsigned int pw[20];
#pragma unroll
    for (int i = 0; i < 20; i++) {
        half2 a = { (_Float16)(s[2 * i] * inv), (_Float16)(s[2 * i + 1] * inv) };
        pw[i] = __builtin_bit_cast(unsigned int, a);
    }

    __syncthreads();   // kk becomes output staging

    float o[24];
    const uint4* vbase = (const uint4*)vT + (line * 4 + head) * 121;
#pragma unroll
    for (int hd = 0; hd < 24; hd++) {
        unsigned int vv[20];
#pragma unroll
        for (int j = 0; j < 5; j++) *(uint4*)&vv[j * 4] = vbase[hd * 5 + j];
        float a = 0.f;
#pragma unroll
        for (int i = 0; i < 20; i++) a = fdot2(vv[i], pw[i], a);
        o[hd] = a;
    }

    {
        _Float16 tm[24];
#pragma unroll
        for (int j = 0; j < 24; j++) tm[j] = (_Float16)o[j];
        _Float16* dA = &kk[(line * 40 + ql) * 104 + head * 24];
#pragma unroll
        for (int j = 0; j < 3; j++) ((uint4*)dA)[j] = ((uint4*)tm)[j];
    }
    __syncthreads();

    // flush 160 rows x 96 f16 to osum[smap(r,l)]
    uint4* dst = (uint4*)osum;
    for (int i = t; i < 1920; i += 640) {
        int row = i / 12, seg = i % 12;
        int s2 = smap(r0 + row / 40, row % 40);
        size_t di = ((size_t)(b * 64000 + s2)) * 12 + seg;
        uint4 v = *(const uint4*)&kk[row * 104 + seg * 8];
        if (ACC) {
            half8 a = __builtin_bit_cast(half8, dst[di]);
            half8 c = __builtin_bit_cast(half8, v);
            dst[di] = __builtin_bit_cast(uint4, a + c);
        } else {
            dst[di] = v;
        }
    }
}

// ---------------- proj GEMM: out[b][c][s] = proj_w @ osum[b][s][96] + pb ----------------
__global__ __launch_bounds__(256) void k_proj(const _Float16* __restrict__ osum,
                                              const _Float16* __restrict__ wp,  // [96][96]
                                              const float* __restrict__ pb,
                                              float* __restrict__ out) {
    __shared__ _Float16 A[9216];
    __shared__ float bias_s[96];
    int t = threadIdx.x;
    int bid = blockIdx.x;
    int b = bid / 500;
    int s0 = (bid % 500) * 128;
    for (int i = t; i < 1152; i += 256) ((uint4*)A)[i] = ((const uint4*)wp)[i];
    if (t < 96) bias_s[t] = pb[t];
    __syncthreads();

    int ws = t >> 6, lane = t & 63;
    int n = lane & 31, kg = lane >> 5;
    int s = s0 + ws * 32 + n;

    const uint4* brow = (const uint4*)(osum + ((size_t)(b * 64000 + s0 + ws * 32 + n)) * 96);
    uint4 bf[6];
#pragma unroll
    for (int kc = 0; kc < 6; kc++) bf[kc] = brow[kc * 2 + kg];

    floatx16 acc[3];
#pragma unroll
    for (int mt = 0; mt < 3; mt++)
#pragma unroll
        for (int r = 0; r < 16; r++) acc[mt][r] = 0.f;

#pragma unroll
    for (int kc = 0; kc < 6; kc++) {
        half8 bfh = __builtin_bit_cast(half8, bf[kc]);
#pragma unroll
        for (int mt = 0; mt < 3; mt++) {
            uint4 au = *(const uint4*)&A[(mt * 32 + n) * 96 + kc * 16 + kg * 8];
            acc[mt] = __builtin_amdgcn_mfma_f32_32x32x16_f16(__builtin_bit_cast(half8, au), bfh, acc[mt], 0, 0, 0);
        }
    }

#pragma unroll
    for (int mt = 0; mt < 3; mt++)
#pragma unroll
        for (int r = 0; r < 16; r++) {
            int m = mt * 32 + (r & 3) + 8 * (r >> 2) + 4 * kg;
            out[((size_t)(b * 96 + m)) * 64000 + s] = acc[mt][r] + bias_s[m];
        }
}

extern "C" void kernel_launch(void* const* d_in, const int* in_sizes, int n_in,
                              void* d_out, int out_size, void* d_ws, size_t ws_size,
                              hipStream_t stream) {
    const float* x      = (const float*)d_in[0];
    const float* pos    = (const float*)d_in[1];
    const float* qkv_w  = (const float*)d_in[2];
    const float* qkv_b  = (const float*)d_in[3];
    const float* lp1_w  = (const float*)d_in[4];
    const float* lp1_b  = (const float*)d_in[5];
    const float* lp2_w  = (const float*)d_in[6];
    const float* lp2_b  = (const float*)d_in[7];
    const float* mod1_w = (const float*)d_in[8];
    const float* mod1_b = (const float*)d_in[9];
    const float* mod2_w = (const float*)d_in[10];
    const float* mod2_b = (const float*)d_in[11];
    // d_in[12..16]: pa_w, pa_b, R6_d, R6_h, R6_w — provably no-ops (see header)
    const float* proj_w = (const float*)d_in[17];
    const float* proj_b = (const float*)d_in[18];
    float* out = (float*)d_out;
    float* ws = (float*)d_ws;

    // f16 buffers (sizes in f32-float units of ws):
    _Float16* bufA = (_Float16*)ws;                        // 12.288M f16: c3/B0 -> xm
    _Float16* bufB = (_Float16*)(ws + 6144000);            // 12.288M f16: C2/D -> osum
    _Float16* qA   = (_Float16*)(ws + 12288000);           // 36.864M f16
    _Float16* in_t = qA;                                   // pos f16 [s][c], dead before qkv
    _Float16* wf   = (_Float16*)(ws + 30720000);           // 248,832 f16
    _Float16* wq   = (_Float16*)(ws + 30844416);           // 27,648 f16
    _Float16* wpj  = (_Float16*)(ws + 30858240);           // 9,216 f16
    _Float16* wfold= (_Float16*)(ws + 30862848);           // 9,216 f16
    _Float16* wm2  = (_Float16*)(ws + 30867456);           // 9,216 f16
    float* bfold   = ws + 30872064;                        // 96 f32
    float* raw     = ws + 30872160;                        // 768 f32 (raw0 | raw1)
    float* raw0 = raw, *raw1 = raw + 384;

    k_cvt_in<<<2016, 256, 0, stream>>>(pos, in_t);
    k_cvt_w<<<972, 256, 0, stream>>>(lp1_w, wf, raw);     // block 0 zeroes raw
    k_fold<<<36, 256, 0, stream>>>(lp2_w, lp2_b, mod1_w, mod1_b, wfold, bfold);
    k_cvt_f16<<<36, 256, 0, stream>>>(mod2_w, wm2, 9216);
    k_cvt_f16<<<108, 256, 0, stream>>>(qkv_w, wq, 27648);
    k_cvt_f16<<<36, 256, 0, stream>>>(proj_w, wpj, 9216);

    // c3 = conv3(pos)  [f16, [b][s][96]]
    k_conv3_v8<<<500, 256, 0, stream>>>(in_t, wf, lp1_b, bufA);
    // B0 = gelu(IN(c3)) in-place (finalize fused into ng16)
    k_stats_sc<<<500, 192, 0, stream>>>(bufA, raw0);
    k_ng16<<<1500, 256, 0, stream>>>(bufA, raw0);
    // C2 = W' @ B0 + b'   (folded lp2 -> mod1)
    k_gemm96<0><<<1000, 256, 0, stream>>>(bufA, wfold, bfold, nullptr, bufB);
    // D = gelu(IN(C2)) in-place
    k_stats_sc<<<500, 192, 0, stream>>>(bufB, raw1);
    k_ng16<<<1500, 256, 0, stream>>>(bufB, raw1);
    // xm = x * sigmoid(mod2 @ D + b)   [f16 [b][s][96], into bufA (B0 dead)]
    k_gemm96<1><<<1000, 256, 0, stream>>>(bufB, wm2, mod2_b, x, bufA);

    // qkv ONCE (s-order); qA overwrites in_t (dead)
    k_qkv<<<1000, 256, 0, stream>>>(bufA, wq, qkv_b, qA);
    // attention: axis 2 writes osum (contiguous), axes 0/1 accumulate
    k_attn<2, false><<<800, 640, 0, stream>>>(qA, bufB);
    k_attn<0, true ><<<800, 640, 0, stream>>>(qA, bufB);
    k_attn<1, true ><<<800, 640, 0, stream>>>(qA, bufB);

    // out = proj(osum)
    k_proj<<<1000, 256, 0, stream>>>(bufB, wpj, proj_b, out);
}